// Round 3
// baseline (1834.855 us; speedup 1.0000x reference)
//
#include <hip/hip_runtime.h>

// Problem constants
#define Bn 2
#define Mn 25000
#define Nn 100000
#define Kn 16
#define MK (Mn*Kn)          // 400000 points per batch
#define GN_EPS 1e-5f
#define NEG_BIG (-3.402823466e+38f)

// ws layout (float offsets). First WS_ZERO_FLOATS are atomic accumulators (zeroed).
#define S1_OFF   0      // [2][4]    sums of x_c
#define S2_OFF   8      // [2][10]   upper-tri second moments of x
#define ER1_OFF  32     // [2][64]   sum of r1 per channel
#define GRAM_OFF 160    // [2][4096] Gram of r1
#define WS_ZERO_FLOATS 8352
#define A1_OFF   8352   // [2][64] gn1 scale
#define C1_OFF   8480   // [2][64] gn1 shift
#define A2_OFF   8608   // [2][64] gn2 scale
#define C2_OFF   8736   // [2][64] gn2 shift
#define BEFF_OFF 8864   // [64]    effective bias for h2
#define WEFF_OFF 8928   // [64*64] at_w1 @ pe_w2
#define EH_OFF   13024  // [2][64] E[h2]
#define EQ_OFF   13152  // [2][64] E[h2^2]
#define WF16_OFF 13280  // [3][64][64] f16 weights (w2, aw1, aw2) — 6144 floats
// total floats: 19424 (~78 KB)

typedef float v2f __attribute__((ext_vector_type(2)));
typedef _Float16 hf8 __attribute__((ext_vector_type(8)));
typedef _Float16 hf2 __attribute__((ext_vector_type(2)));
typedef float f32x16 __attribute__((ext_vector_type(16)));

__device__ __forceinline__ f32x16 mfma16(hf8 a, hf8 b, f32x16 c) {
    return __builtin_amdgcn_mfma_f32_32x32x16_f16(a, b, c, 0, 0, 0);
}
__device__ __forceinline__ f32x16 splat16(float v) {
    f32x16 x;
#pragma unroll
    for (int r = 0; r < 16; ++r) x[r] = v;
    return x;
}

// Compute local_pattern x[4] for point (b,i) then r1 = relu(a1*h1 + c1), h1 = W1 x + b1.
__device__ __forceinline__ void compute_r1v(
    int b, int i,
    const float* __restrict__ q, const float* __restrict__ kx,
    const int* __restrict__ idx,
    const float* __restrict__ w1, const float* __restrict__ b1,
    const float* __restrict__ a1, const float* __restrict__ c1,
    v2f* r1v)
{
    const int mm = i >> 4;
    const int id = idx[b*MK + i];
    const float qx = q[(b*3 + 0)*Mn + mm];
    const float qy = q[(b*3 + 1)*Mn + mm];
    const float qz = q[(b*3 + 2)*Mn + mm];
    const float ox = kx[(b*3 + 0)*Nn + id] - qx;
    const float oy = kx[(b*3 + 1)*Nn + id] - qy;
    const float oz = kx[(b*3 + 2)*Nn + id] - qz;
    const float d  = sqrtf(ox*ox + oy*oy + oz*oz);
    const float inv = 1.0f / fmaxf(d, 1e-12f);
    const float x0 = ox*inv, x1 = oy*inv, x2 = oz*inv, x3 = d;
#pragma unroll
    for (int o = 0; o < 64; ++o) {
        const float4 w = ((const float4*)w1)[o];
        float h = fmaf(w.x, x0, fmaf(w.y, x1, fmaf(w.z, x2, fmaf(w.w, x3, b1[o]))));
        h = fmaf(a1[o], h, c1[o]);
        h = fmaxf(h, 0.f);
        if (o & 1) r1v[o >> 1].y = h; else r1v[o >> 1].x = h;
    }
}

__device__ __forceinline__ float waveSum(float v) {
#pragma unroll
    for (int s = 32; s; s >>= 1) v += __shfl_down(v, s, 64);
    return v;
}

// ---------------- Kernel A: raw moments of local_pattern (per batch) ----------------
__global__ __launch_bounds__(256) void stats1_kernel(
    const float* __restrict__ q, const float* __restrict__ kx,
    const int* __restrict__ idx, float* __restrict__ ws)
{
    const int b = blockIdx.y;
    float s[4]  = {0.f, 0.f, 0.f, 0.f};
    float m2[10] = {0.f,0.f,0.f,0.f,0.f,0.f,0.f,0.f,0.f,0.f};
    for (int i = blockIdx.x*blockDim.x + threadIdx.x; i < MK; i += gridDim.x*blockDim.x) {
        const int mm = i >> 4;
        const int id = idx[b*MK + i];
        const float ox = kx[(b*3+0)*Nn + id] - q[(b*3+0)*Mn + mm];
        const float oy = kx[(b*3+1)*Nn + id] - q[(b*3+1)*Mn + mm];
        const float oz = kx[(b*3+2)*Nn + id] - q[(b*3+2)*Mn + mm];
        const float d  = sqrtf(ox*ox + oy*oy + oz*oz);
        const float inv = 1.0f / fmaxf(d, 1e-12f);
        const float x0 = ox*inv, x1 = oy*inv, x2 = oz*inv, x3 = d;
        s[0] += x0; s[1] += x1; s[2] += x2; s[3] += x3;
        m2[0] += x0*x0; m2[1] += x0*x1; m2[2] += x0*x2; m2[3] += x0*x3;
        m2[4] += x1*x1; m2[5] += x1*x2; m2[6] += x1*x3;
        m2[7] += x2*x2; m2[8] += x2*x3; m2[9] += x3*x3;
    }
#pragma unroll
    for (int j = 0; j < 4; ++j)  s[j]  = waveSum(s[j]);
#pragma unroll
    for (int j = 0; j < 10; ++j) m2[j] = waveSum(m2[j]);
    if ((threadIdx.x & 63) == 0) {
#pragma unroll
        for (int j = 0; j < 4; ++j)  atomicAdd(&ws[S1_OFF + b*4  + j], s[j]);
#pragma unroll
        for (int j = 0; j < 10; ++j) atomicAdd(&ws[S2_OFF + b*10 + j], m2[j]);
    }
}

// ---------------- Kernel B: gn1 affine coeffs + Weff/beff + f16 weights ----------------
__global__ void prep1_kernel(
    const float* __restrict__ ws_r,
    const float* __restrict__ w1, const float* __restrict__ b1,
    const float* __restrict__ g1, const float* __restrict__ be1,
    const float* __restrict__ w2, const float* __restrict__ pe_b2,
    const float* __restrict__ aw1, const float* __restrict__ ab1,
    const float* __restrict__ aw2,
    float* __restrict__ ws)
{
    __shared__ float Eh[2][64], Eq[2][64];
    const int t = threadIdx.x;
    if (t < 128) {
        const int b = t >> 6, o = t & 63;
        const double inv = 1.0 / (double)MK;
        double mu[4];
#pragma unroll
        for (int c = 0; c < 4; ++c) mu[c] = (double)ws_r[S1_OFF + b*4 + c] * inv;
        double m2[4][4];
        {
            const int map[4][4] = {{0,1,2,3},{1,4,5,6},{2,5,7,8},{3,6,8,9}};
#pragma unroll
            for (int c = 0; c < 4; ++c)
#pragma unroll
                for (int c2 = 0; c2 < 4; ++c2)
                    m2[c][c2] = (double)ws_r[S2_OFF + b*10 + map[c][c2]] * inv;
        }
        double w[4];
#pragma unroll
        for (int c = 0; c < 4; ++c) w[c] = (double)w1[o*4 + c];
        double s = 0.0, qd = 0.0;
#pragma unroll
        for (int c = 0; c < 4; ++c) {
            s += w[c] * mu[c];
#pragma unroll
            for (int c2 = 0; c2 < 4; ++c2) qd += w[c]*w[c2]*m2[c][c2];
        }
        const double bb = (double)b1[o];
        Eh[b][o] = (float)(s + bb);
        Eq[b][o] = (float)(qd + 2.0*bb*s + bb*bb);
    }
    __syncthreads();
    if (t < 128) {
        const int b = t >> 6, o = t & 63, g = o & ~7;
        float mg = 0.f, qg = 0.f;
#pragma unroll
        for (int j = 0; j < 8; ++j) { mg += Eh[b][g + j]; qg += Eq[b][g + j]; }
        mg *= 0.125f; qg *= 0.125f;
        const float var = fmaxf(qg - mg*mg, 0.f);
        const float a = g1[o] / sqrtf(var + GN_EPS);
        ws[A1_OFF + b*64 + o] = a;
        ws[C1_OFF + b*64 + o] = be1[o] - mg*a;
    }
    // Weff = at_w1 @ pe_w2 ;  beff = at_w1 @ pe_b2 + at_b1
    for (int e = t; e < 4096; e += blockDim.x) {
        const int o = e >> 6, c = e & 63;
        float acc = 0.f;
        for (int d = 0; d < 64; ++d) acc = fmaf(aw1[o*64 + d], w2[d*64 + c], acc);
        ws[WEFF_OFF + e] = acc;
    }
    if (t < 64) {
        float acc = ab1[t];
        for (int d = 0; d < 64; ++d) acc = fmaf(aw1[t*64 + d], pe_b2[d], acc);
        ws[BEFF_OFF + t] = acc;
    }
    // f16 copies of the three 64x64 weight matrices for pass3 B-operands
    _Float16* WF = (_Float16*)(ws + WF16_OFF);
    for (int e = t; e < 4096; e += blockDim.x) {
        WF[e]        = (_Float16)w2[e];
        WF[4096 + e] = (_Float16)aw1[e];
        WF[8192 + e] = (_Float16)aw2[e];
    }
}

// ---------------- Kernel C: r1 sums + Gram(r1) via MFMA ----------------
__global__ __launch_bounds__(256, 4) void pass2_kernel(
    const float* __restrict__ q, const float* __restrict__ kx,
    const int* __restrict__ idx,
    const float* __restrict__ w1, const float* __restrict__ b1,
    const float* __restrict__ cws, float* __restrict__ ws)
{
    __shared__ __align__(16) _Float16 XT[64][264];   // [ch][pt], padded
    const int b = blockIdx.y;
    const int tid = threadIdx.x, lane = tid & 63, wv = tid >> 6;
    const float* a1 = cws + A1_OFF + (b << 6);
    const float* c1 = cws + C1_OFF + (b << 6);

    v2f sums[32];
#pragma unroll
    for (int c = 0; c < 32; ++c) { sums[c].x = 0.f; sums[c].y = 0.f; }
    f32x16 acc = splat16(0.f);

    const int i0 = 32*(wv >> 1), j0 = 32*(wv & 1);
    const int rowA = i0 + (lane & 31), rowB = j0 + (lane & 31);
    const int klo = (lane >> 5) * 8;

    for (int base = blockIdx.x * 256; base < MK; base += gridDim.x * 256) {
        const int i = base + tid;
        v2f r1v[32];
        if (i < MK) {
            compute_r1v(b, i, q, kx, idx, w1, b1, a1, c1, r1v);
        } else {
#pragma unroll
            for (int c = 0; c < 32; ++c) { r1v[c].x = 0.f; r1v[c].y = 0.f; }
        }
#pragma unroll
        for (int c = 0; c < 32; ++c) sums[c] += r1v[c];
#pragma unroll
        for (int o2 = 0; o2 < 32; ++o2) {
            XT[2*o2    ][tid] = (_Float16)r1v[o2].x;
            XT[2*o2 + 1][tid] = (_Float16)r1v[o2].y;
        }
        __syncthreads();
#pragma unroll
        for (int ks = 0; ks < 16; ++ks) {
            hf8 af = *(const hf8*)&XT[rowA][16*ks + klo];
            hf8 bf = *(const hf8*)&XT[rowB][16*ks + klo];
            acc = mfma16(af, bf, acc);
        }
        __syncthreads();
    }
#pragma unroll
    for (int o = 0; o < 64; ++o) {
        float s = (o & 1) ? sums[o >> 1].y : sums[o >> 1].x;
        s = waveSum(s);
        if (lane == 0) atomicAdd(&ws[ER1_OFF + b*64 + o], s);
    }
#pragma unroll
    for (int r = 0; r < 16; ++r) {
        const int gi = i0 + (r & 3) + 8*(r >> 2) + 4*(lane >> 5);
        const int gj = j0 + (lane & 31);
        atomicAdd(&ws[GRAM_OFF + b*4096 + gi*64 + gj], acc[r]);
    }
}

// ---------------- Kernel D1: E[h2], E[h2^2] from Gram (one wave per (b,o)) ----------------
__global__ __launch_bounds__(64) void prep2a_kernel(
    const float* __restrict__ ws_r, float* __restrict__ ws)
{
    const int b = blockIdx.x >> 6, o = blockIdx.x & 63;
    const int c = threadIdx.x;                       // 64 threads
    const float* G  = ws_r + GRAM_OFF + b*4096;
    const float* Wo = ws_r + WEFF_OFF + o*64;
    double rowacc = 0.0;
    for (int c2 = 0; c2 < 64; ++c2)
        rowacc += (double)G[c*64 + c2] * (double)Wo[c2];
    double quad = (double)Wo[c] * rowacc;
    double dot  = (double)Wo[c] * (double)ws_r[ER1_OFF + b*64 + c];
#pragma unroll
    for (int s = 32; s; s >>= 1) {
        quad += __shfl_down(quad, s, 64);
        dot  += __shfl_down(dot,  s, 64);
    }
    if (c == 0) {
        const double invMK = 1.0 / (double)MK;
        dot *= invMK; quad *= invMK;
        const double beff = (double)ws_r[BEFF_OFF + o];
        ws[EH_OFF + b*64 + o] = (float)(dot + beff);
        ws[EQ_OFF + b*64 + o] = (float)(quad + 2.0*beff*dot + beff*beff);
    }
}

// ---------------- Kernel D2: gn2 affine coeffs ----------------
__global__ void prep2b_kernel(const float* __restrict__ ws_r,
                              const float* __restrict__ g2, const float* __restrict__ be2,
                              float* __restrict__ ws)
{
    const int t = threadIdx.x;
    if (t >= 128) return;
    const int b = t >> 6, o = t & 63, g = o & ~7;
    float mg = 0.f, qg = 0.f;
#pragma unroll
    for (int j = 0; j < 8; ++j) {
        mg += ws_r[EH_OFF + b*64 + g + j];
        qg += ws_r[EQ_OFF + b*64 + g + j];
    }
    mg *= 0.125f; qg *= 0.125f;
    const float var = fmaxf(qg - mg*mg, 0.f);
    const float a = g2[o] / sqrtf(var + GN_EPS);
    ws[A2_OFF + b*64 + o] = a;
    ws[C2_OFF + b*64 + o] = be2[o] - mg*a;
}

// ---------------- Kernel E: fused MFMA forward, wave-private pipeline ----------------
// 128 points/block, 4 waves; wave w owns points 32w..32w+31 (its own X rows),
// so LDS round-trips between GEMMs need no __syncthreads (per-wave in-order LDS).
__global__ __launch_bounds__(256, 4) void pass3_kernel(
    const float* __restrict__ q, const float* __restrict__ kx,
    const int* __restrict__ idx, const int* __restrict__ mask,
    const float* __restrict__ w1,  const float* __restrict__ b1,
    const float* __restrict__ b2,  const float* __restrict__ ab1,
    const float* __restrict__ ab2,
    const float* __restrict__ cws, float* __restrict__ out)
{
    __shared__ __align__(16) _Float16 Xs[128 * 72];   // activations [pt][ch], pad 72
    float* O = (float*)Xs;                            // aliased after barrier: [64][9]

    const int b = blockIdx.y;
    const int base = blockIdx.x * 128;                // 3125*128 == MK exactly
    const int tid = threadIdx.x;
    const int lane = tid & 63, wv = tid >> 6;
    const int colA = lane & 31;
    const int klo = (lane >> 5) * 8;
    const _Float16* WF = (const _Float16*)(cws + WF16_OFF);

    // ---- stage 1: r1 -> Xs. thread (p = tid&127, half hh = tid>>7) does 32 channels ----
    {
        const int p  = tid & 127;
        const int hh = tid >> 7;
        const int i  = base + p;
        const int mm = i >> 4;
        const int id = idx[(size_t)b*MK + i];
        const float qx = q[(b*3 + 0)*Mn + mm];
        const float qy = q[(b*3 + 1)*Mn + mm];
        const float qz = q[(b*3 + 2)*Mn + mm];
        const float ox = kx[(b*3 + 0)*Nn + id] - qx;
        const float oy = kx[(b*3 + 1)*Nn + id] - qy;
        const float oz = kx[(b*3 + 2)*Nn + id] - qz;
        const float d  = sqrtf(ox*ox + oy*oy + oz*oz);
        const float inv = 1.0f / fmaxf(d, 1e-12f);
        const float x0 = ox*inv, x1 = oy*inv, x2 = oz*inv, x3 = d;
        const float* a1 = cws + A1_OFF + (b << 6);
        const float* c1 = cws + C1_OFF + (b << 6);
#pragma unroll
        for (int u = 0; u < 16; ++u) {
            const int o0 = 32*hh + 2*u;
            const float4 wA = ((const float4*)w1)[o0];
            const float4 wB = ((const float4*)w1)[o0 + 1];
            float hA = fmaf(wA.x, x0, fmaf(wA.y, x1, fmaf(wA.z, x2, fmaf(wA.w, x3, b1[o0]))));
            float hB = fmaf(wB.x, x0, fmaf(wB.y, x1, fmaf(wB.z, x2, fmaf(wB.w, x3, b1[o0+1]))));
            hA = fmaxf(fmaf(a1[o0],     hA, c1[o0]),     0.f);
            hB = fmaxf(fmaf(a1[o0 + 1], hB, c1[o0 + 1]), 0.f);
            hf2 pk; pk[0] = (_Float16)hA; pk[1] = (_Float16)hB;
            *(hf2*)&Xs[p*72 + o0] = pk;
        }
    }
    // mask bits for this wave's 32-pt group (bit r = point 32*wv + r)
    const bool lvb = (lane < 32) && (mask[(size_t)b*MK + base + 32*wv + lane] != 0);
    const unsigned mb32 = (unsigned)__ballot(lvb);

    __syncthreads();

    const int rowA = 32*wv + colA;   // this wave's A rows (points)

    // ---- GEMM1: pe = r1 @ w2^T + b2 ----
    f32x16 pe0 = splat16(b2[colA]);
    f32x16 pe1 = splat16(b2[32 + colA]);
#pragma unroll
    for (int ks = 0; ks < 4; ++ks) {
        const int off = 16*ks + klo;
        hf8 a   = *(const hf8*)&Xs[rowA*72 + off];
        hf8 b0f = *(const hf8*)&WF[(colA)*64 + off];
        hf8 b1f = *(const hf8*)&WF[(32 + colA)*64 + off];
        pe0 = mfma16(a, b0f, pe0);
        pe1 = mfma16(a, b1f, pe1);
    }
#pragma unroll
    for (int r = 0; r < 16; ++r) {
        const int row = 32*wv + (r & 3) + 8*(r >> 2) + 4*(lane >> 5);
        Xs[row*72 + colA]      = (_Float16)pe0[r];
        Xs[row*72 + 32 + colA] = (_Float16)pe1[r];
    }

    // ---- GEMM2: h2 = pe @ aw1^T + ab1, then gn2 affine + relu ----
    f32x16 h0 = splat16(ab1[colA]);
    f32x16 h1 = splat16(ab1[32 + colA]);
#pragma unroll
    for (int ks = 0; ks < 4; ++ks) {
        const int off = 16*ks + klo;
        hf8 a   = *(const hf8*)&Xs[rowA*72 + off];
        hf8 b0f = *(const hf8*)&WF[4096 + (colA)*64 + off];
        hf8 b1f = *(const hf8*)&WF[4096 + (32 + colA)*64 + off];
        h0 = mfma16(a, b0f, h0);
        h1 = mfma16(a, b1f, h1);
    }
    {
        const float a2l = cws[A2_OFF + (b << 6) + colA];
        const float a2h = cws[A2_OFF + (b << 6) + 32 + colA];
        const float c2l = cws[C2_OFF + (b << 6) + colA];
        const float c2h = cws[C2_OFF + (b << 6) + 32 + colA];
#pragma unroll
        for (int r = 0; r < 16; ++r) {
            const int row = 32*wv + (r & 3) + 8*(r >> 2) + 4*(lane >> 5);
            Xs[row*72 + colA]      = (_Float16)fmaxf(fmaf(a2l, h0[r], c2l), 0.f);
            Xs[row*72 + 32 + colA] = (_Float16)fmaxf(fmaf(a2h, h1[r], c2h), 0.f);
        }
    }

    // ---- GEMM3: logits = r2 @ aw2^T + ab2 ----
    f32x16 l0 = splat16(ab2[colA]);
    f32x16 l1 = splat16(ab2[32 + colA]);
#pragma unroll
    for (int ks = 0; ks < 4; ++ks) {
        const int off = 16*ks + klo;
        hf8 a   = *(const hf8*)&Xs[rowA*72 + off];
        hf8 b0f = *(const hf8*)&WF[8192 + (colA)*64 + off];
        hf8 b1f = *(const hf8*)&WF[8192 + (32 + colA)*64 + off];
        l0 = mfma16(a, b0f, l0);
        l1 = mfma16(a, b1f, l1);
    }

    __syncthreads();   // all X reads done; O may now alias X

    // ---- masked softmax over K=16 + weighted pe sum -> O[ch][m_local] ----
    {
        const int rbase4 = 4*(lane >> 5);
        auto softmax_tile = [&](const f32x16& lg, const f32x16& pe, int j) {
#pragma unroll
            for (int mh = 0; mh < 2; ++mh) {
                float lv[8];
                float mx = NEG_BIG;
#pragma unroll
                for (int rr = 0; rr < 8; ++rr) {
                    const int r = 8*mh + rr;
                    const int row = (r & 3) + 8*(r >> 2) + rbase4;
                    const float x = ((mb32 >> row) & 1u) ? lg[r] : NEG_BIG;
                    lv[rr] = x;
                    mx = fmaxf(mx, x);
                }
                mx = fmaxf(mx, __shfl_xor(mx, 32, 64));
                float se = 0.f, sw = 0.f;
#pragma unroll
                for (int rr = 0; rr < 8; ++rr) {
                    const float e = __expf(lv[rr] - mx);
                    se += e;
                    sw = fmaf(e, pe[8*mh + rr], sw);
                }
                se += __shfl_xor(se, 32, 64);
                sw += __shfl_xor(sw, 32, 64);
                if (lane < 32)
                    O[(32*j + lane)*9 + (2*wv + mh)] = sw / se;
            }
        };
        softmax_tile(l0, pe0, 0);
        softmax_tile(l1, pe1, 1);
    }
    __syncthreads();

    // ---- coalesced output: 64 ch x 8 m per block ----
    if (tid < 128) {
        const int o = tid >> 1, mq = (tid & 1) * 4;
        float4 v;
        v.x = O[o*9 + mq];     v.y = O[o*9 + mq + 1];
        v.z = O[o*9 + mq + 2]; v.w = O[o*9 + mq + 3];
        *(float4*)&out[((size_t)b*64 + o)*Mn + (base >> 4) + mq] = v;
    }
}

extern "C" void kernel_launch(void* const* d_in, const int* in_sizes, int n_in,
                              void* d_out, int out_size, void* d_ws, size_t ws_size,
                              hipStream_t stream) {
    (void)in_sizes; (void)n_in; (void)out_size; (void)ws_size;
    const float* q    = (const float*)d_in[0];
    const float* kx   = (const float*)d_in[1];
    const int*   idx  = (const int*)  d_in[2];
    const int*   mask = (const int*)  d_in[3];
    const float* w1   = (const float*)d_in[4];
    const float* b1   = (const float*)d_in[5];
    const float* g1   = (const float*)d_in[6];
    const float* be1  = (const float*)d_in[7];
    const float* w2   = (const float*)d_in[8];
    const float* b2   = (const float*)d_in[9];
    const float* aw1  = (const float*)d_in[10];
    const float* ab1  = (const float*)d_in[11];
    const float* g2   = (const float*)d_in[12];
    const float* be2  = (const float*)d_in[13];
    const float* aw2  = (const float*)d_in[14];
    const float* ab2  = (const float*)d_in[15];
    float* out = (float*)d_out;
    float* ws  = (float*)d_ws;

    hipMemsetAsync(ws, 0, WS_ZERO_FLOATS * sizeof(float), stream);

    stats1_kernel<<<dim3(512, Bn), 256, 0, stream>>>(q, kx, idx, ws);
    prep1_kernel<<<1, 256, 0, stream>>>(ws, w1, b1, g1, be1, w2, b2, aw1, ab1, aw2, ws);
    pass2_kernel<<<dim3(512, Bn), 256, 0, stream>>>(q, kx, idx, w1, b1, ws, ws);
    prep2a_kernel<<<128, 64, 0, stream>>>(ws, ws);
    prep2b_kernel<<<1, 128, 0, stream>>>(ws, g2, be2, ws);
    pass3_kernel<<<dim3(MK/128, Bn), 256, 0, stream>>>(
        q, kx, idx, mask, w1, b1, b2, ab1, ab2, ws, out);
}

// Round 4
// 289.039 us; speedup vs baseline: 6.3481x; 6.3481x over previous
//
#include <hip/hip_runtime.h>

// Problem constants
#define Bn 2
#define Mn 25000
#define Nn 100000
#define Kn 16
#define MK (Mn*Kn)          // 400000 points per batch
#define GN_EPS 1e-5f
#define NEG_BIG (-3.402823466e+38f)

#define G1 256              // stats1 blocks per batch
#define G2 512              // pass2 blocks per batch

// ws layout (float offsets). No atomic accumulators — every region is fully
// written by a producer kernel before its consumer reads it (no memset needed).
#define A1_OFF   0        // [2][64] gn1 scale
#define C1_OFF   128      // [2][64] gn1 shift
#define BEFF_OFF 256      // [64]    effective bias for h2 (at_w1@pe_b2 + at_b1)
#define A2_OFF   320      // [2][64] gn2 scale
#define C2_OFF   448      // [2][64] gn2 shift
#define SP_OFF   576      // [2][G1][16]  stats1 partials (14 used)
#define YP_OFF   8768     // [2][G2][128] pass2 partials (Σy | Σy²)
#define WF16_OFF 139840   // [4][64][64] f16 weights: w2, aw1, aw2, Weff
// total floats: 148032 (~592 KB)

typedef float v2f __attribute__((ext_vector_type(2)));
typedef _Float16 hf8 __attribute__((ext_vector_type(8)));
typedef _Float16 hf4 __attribute__((ext_vector_type(4)));
typedef _Float16 hf2 __attribute__((ext_vector_type(2)));
typedef float f32x16 __attribute__((ext_vector_type(16)));

__device__ __forceinline__ f32x16 mfma16(hf8 a, hf8 b, f32x16 c) {
    return __builtin_amdgcn_mfma_f32_32x32x16_f16(a, b, c, 0, 0, 0);
}
__device__ __forceinline__ f32x16 splat16(float v) {
    f32x16 x;
#pragma unroll
    for (int r = 0; r < 16; ++r) x[r] = v;
    return x;
}

__device__ __forceinline__ float waveSum(float v) {
#pragma unroll
    for (int s = 32; s; s >>= 1) v += __shfl_down(v, s, 64);
    return v;
}

// ---------------- Kernel A: raw moments of local_pattern -> per-block partials ----------------
__global__ __launch_bounds__(256) void stats1_kernel(
    const float* __restrict__ q, const float* __restrict__ kx,
    const int* __restrict__ idx, float* __restrict__ ws)
{
    __shared__ float red[4][16];
    const int b = blockIdx.y;
    float v[14];
#pragma unroll
    for (int j = 0; j < 14; ++j) v[j] = 0.f;
    for (int i = blockIdx.x*blockDim.x + threadIdx.x; i < MK; i += gridDim.x*blockDim.x) {
        const int mm = i >> 4;
        const int id = idx[b*MK + i];
        const float ox = kx[(b*3+0)*Nn + id] - q[(b*3+0)*Mn + mm];
        const float oy = kx[(b*3+1)*Nn + id] - q[(b*3+1)*Mn + mm];
        const float oz = kx[(b*3+2)*Nn + id] - q[(b*3+2)*Mn + mm];
        const float d  = sqrtf(ox*ox + oy*oy + oz*oz);
        const float inv = 1.0f / fmaxf(d, 1e-12f);
        const float x0 = ox*inv, x1 = oy*inv, x2 = oz*inv, x3 = d;
        v[0] += x0; v[1] += x1; v[2] += x2; v[3] += x3;
        v[4] += x0*x0; v[5] += x0*x1; v[6] += x0*x2; v[7] += x0*x3;
        v[8] += x1*x1; v[9] += x1*x2; v[10] += x1*x3;
        v[11] += x2*x2; v[12] += x2*x3; v[13] += x3*x3;
    }
    const int lane = threadIdx.x & 63, wv = threadIdx.x >> 6;
#pragma unroll
    for (int j = 0; j < 14; ++j) v[j] = waveSum(v[j]);
    if (lane == 0) {
#pragma unroll
        for (int j = 0; j < 14; ++j) red[wv][j] = v[j];
    }
    __syncthreads();
    if (threadIdx.x < 14)
        ws[SP_OFF + ((size_t)b*G1 + blockIdx.x)*16 + threadIdx.x] =
            red[0][threadIdx.x] + red[1][threadIdx.x] + red[2][threadIdx.x] + red[3][threadIdx.x];
}

// ---------------- Kernel B: reduce stats + gn1 coeffs + Weff/beff + f16 weights ----------------
__global__ void prep1_kernel(
    const float* __restrict__ ws_r,
    const float* __restrict__ w1, const float* __restrict__ b1,
    const float* __restrict__ g1, const float* __restrict__ be1,
    const float* __restrict__ w2, const float* __restrict__ pe_b2,
    const float* __restrict__ aw1, const float* __restrict__ ab1,
    const float* __restrict__ aw2,
    float* __restrict__ ws)
{
    __shared__ double S[2][14];
    __shared__ float Eh[2][64], Eq[2][64];
    __shared__ float WL[4096];
    const int t = threadIdx.x;

    if (t < 28) {
        const int b = t / 14, j = t % 14;
        const float* p = ws_r + SP_OFF + (size_t)b*G1*16 + j;
        double acc = 0.0;
        for (int g = 0; g < G1; g += 4)
            acc += (double)p[(g+0)*16] + (double)p[(g+1)*16]
                 + (double)p[(g+2)*16] + (double)p[(g+3)*16];
        S[b][j] = acc;
    }
    __syncthreads();

    if (t < 128) {
        const int b = t >> 6, o = t & 63;
        const double inv = 1.0 / (double)MK;
        double mu[4];
#pragma unroll
        for (int c = 0; c < 4; ++c) mu[c] = S[b][c] * inv;
        double m2[4][4];
        {
            const int map[4][4] = {{0,1,2,3},{1,4,5,6},{2,5,7,8},{3,6,8,9}};
#pragma unroll
            for (int c = 0; c < 4; ++c)
#pragma unroll
                for (int c2 = 0; c2 < 4; ++c2)
                    m2[c][c2] = S[b][4 + map[c][c2]] * inv;
        }
        double w[4];
#pragma unroll
        for (int c = 0; c < 4; ++c) w[c] = (double)w1[o*4 + c];
        double s = 0.0, qd = 0.0;
#pragma unroll
        for (int c = 0; c < 4; ++c) {
            s += w[c] * mu[c];
#pragma unroll
            for (int c2 = 0; c2 < 4; ++c2) qd += w[c]*w[c2]*m2[c][c2];
        }
        const double bb = (double)b1[o];
        Eh[b][o] = (float)(s + bb);
        Eq[b][o] = (float)(qd + 2.0*bb*s + bb*bb);
    }
    __syncthreads();
    if (t < 128) {
        const int b = t >> 6, o = t & 63, g = o & ~7;
        float mg = 0.f, qg = 0.f;
#pragma unroll
        for (int j = 0; j < 8; ++j) { mg += Eh[b][g + j]; qg += Eq[b][g + j]; }
        mg *= 0.125f; qg *= 0.125f;
        const float var = fmaxf(qg - mg*mg, 0.f);
        const float a = g1[o] / sqrtf(var + GN_EPS);
        ws[A1_OFF + b*64 + o] = a;
        ws[C1_OFF + b*64 + o] = be1[o] - mg*a;
    }
    // Weff = at_w1 @ pe_w2 (LDS only) ; beff = at_w1 @ pe_b2 + at_b1
    for (int e = t; e < 4096; e += 256) {
        const int o = e >> 6, c = e & 63;
        float acc = 0.f;
        for (int d = 0; d < 64; ++d) acc = fmaf(aw1[o*64 + d], w2[d*64 + c], acc);
        WL[e] = acc;
    }
    if (t < 64) {
        float acc = ab1[t];
        for (int d = 0; d < 64; ++d) acc = fmaf(aw1[t*64 + d], pe_b2[d], acc);
        ws[BEFF_OFF + t] = acc;
    }
    __syncthreads();
    // f16 weight copies: w2, aw1, aw2, Weff
    _Float16* WF = (_Float16*)(ws + WF16_OFF);
    for (int e = t; e < 4096; e += 256) {
        WF[e]         = (_Float16)w2[e];
        WF[4096 + e]  = (_Float16)aw1[e];
        WF[8192 + e]  = (_Float16)aw2[e];
        WF[12288 + e] = (_Float16)WL[e];
    }
}

// ---------------- Kernel C: Σy, Σy² per channel (y = Weff@r1) via MFMA, partials out ----------------
__global__ __launch_bounds__(256, 4) void pass2_kernel(
    const float* __restrict__ q, const float* __restrict__ kx,
    const int* __restrict__ idx,
    const float* __restrict__ w1, const float* __restrict__ b1,
    const float* __restrict__ cws, float* __restrict__ ws)
{
    __shared__ __align__(16) _Float16 Xs[256 * 72];   // 36 KB
    const int b = blockIdx.y;
    const int tid = threadIdx.x, lane = tid & 63, wv = tid >> 6;
    const int colA = lane & 31;
    const int klo = (lane >> 5) * 8;
    const float* a1 = cws + A1_OFF + (b << 6);
    const float* c1 = cws + C1_OFF + (b << 6);

    // Weff f16 B-fragments, register-held across all chunks
    const _Float16* WFe = (const _Float16*)(cws + WF16_OFF) + 12288;
    hf8 Bf[2][4];
#pragma unroll
    for (int jc = 0; jc < 2; ++jc)
#pragma unroll
        for (int ks = 0; ks < 4; ++ks)
            Bf[jc][ks] = *(const hf8*)&WFe[(jc*32 + colA)*64 + 16*ks + klo];

    float sh[2] = {0.f, 0.f}, sq[2] = {0.f, 0.f};

    for (int base = blockIdx.x * 256; base < MK; base += G2 * 256) {
        const int i = base + tid;
        if (i < MK) {
            const int mm = i >> 4;
            const int id = idx[b*MK + i];
            const float ox = kx[(b*3+0)*Nn + id] - q[(b*3+0)*Mn + mm];
            const float oy = kx[(b*3+1)*Nn + id] - q[(b*3+1)*Mn + mm];
            const float oz = kx[(b*3+2)*Nn + id] - q[(b*3+2)*Mn + mm];
            const float d  = sqrtf(ox*ox + oy*oy + oz*oz);
            const float inv = 1.0f / fmaxf(d, 1e-12f);
            const float x0 = ox*inv, x1 = oy*inv, x2 = oz*inv, x3 = d;
#pragma unroll
            for (int u = 0; u < 16; ++u) {
                hf4 pk;
#pragma unroll
                for (int j = 0; j < 4; ++j) {
                    const int o = 4*u + j;
                    const float4 w = ((const float4*)w1)[o];
                    float h = fmaf(w.x, x0, fmaf(w.y, x1, fmaf(w.z, x2, fmaf(w.w, x3, b1[o]))));
                    h = fmaxf(fmaf(a1[o], h, c1[o]), 0.f);
                    pk[j] = (_Float16)h;
                }
                *(hf4*)&Xs[(size_t)tid*72 + 4*u] = pk;
            }
        } else {
            hf4 z; z[0] = z[1] = z[2] = z[3] = (_Float16)0.f;
#pragma unroll
            for (int u = 0; u < 16; ++u) *(hf4*)&Xs[(size_t)tid*72 + 4*u] = z;
        }
        __syncthreads();
#pragma unroll
        for (int rt = 0; rt < 2; ++rt) {
            hf8 A[4];
            const int row = 64*wv + 32*rt + colA;
#pragma unroll
            for (int ks = 0; ks < 4; ++ks)
                A[ks] = *(const hf8*)&Xs[(size_t)row*72 + 16*ks + klo];
#pragma unroll
            for (int jc = 0; jc < 2; ++jc) {
                f32x16 C = splat16(0.f);
#pragma unroll
                for (int ks = 0; ks < 4; ++ks) C = mfma16(A[ks], Bf[jc][ks], C);
#pragma unroll
                for (int r = 0; r < 16; ++r) {
                    const float vy = C[r];
                    sh[jc] += vy;
                    sq[jc] = fmaf(vy, vy, sq[jc]);
                }
            }
        }
        __syncthreads();
    }

    // cross-half then cross-wave reduce -> one coalesced 128-float partial per block
#pragma unroll
    for (int jc = 0; jc < 2; ++jc) {
        sh[jc] += __shfl_xor(sh[jc], 32, 64);
        sq[jc] += __shfl_xor(sq[jc], 32, 64);
    }
    float* red = (float*)Xs;   // [4][128]
    if (lane < 32) {
        red[wv*128 +       colA] = sh[0];
        red[wv*128 + 32  + colA] = sh[1];
        red[wv*128 + 64  + colA] = sq[0];
        red[wv*128 + 96  + colA] = sq[1];
    }
    __syncthreads();
    if (tid < 128) {
        const float v = red[tid] + red[128 + tid] + red[256 + tid] + red[384 + tid];
        ws[YP_OFF + ((size_t)b*G2 + blockIdx.x)*128 + tid] = v;
    }
}

// ---------------- Kernel D: reduce pass2 partials -> gn2 affine coeffs ----------------
__global__ void prep2_kernel(const float* __restrict__ ws_r,
                             const float* __restrict__ g2, const float* __restrict__ be2,
                             float* __restrict__ ws)
{
    __shared__ double sums[2][128];
    __shared__ float EH[2][64], EQ[2][64];
    const int t = threadIdx.x;   // 256
    {
        const int b = t >> 7, i = t & 127;
        const float* p = ws_r + YP_OFF + (size_t)b*G2*128 + i;
        double acc = 0.0;
        for (int g = 0; g < G2; g += 8) {
            acc += (double)p[(g+0)*128] + (double)p[(g+1)*128]
                 + (double)p[(g+2)*128] + (double)p[(g+3)*128]
                 + (double)p[(g+4)*128] + (double)p[(g+5)*128]
                 + (double)p[(g+6)*128] + (double)p[(g+7)*128];
        }
        sums[b][i] = acc;
    }
    __syncthreads();
    if (t < 128) {
        const int b = t >> 6, o = t & 63;
        const double invMK = 1.0 / (double)MK;
        const double my = sums[b][o] * invMK;
        const double qy = sums[b][64 + o] * invMK;
        const double beff = (double)ws_r[BEFF_OFF + o];
        EH[b][o] = (float)(my + beff);
        EQ[b][o] = (float)(qy + 2.0*beff*my + beff*beff);
    }
    __syncthreads();
    if (t < 128) {
        const int b = t >> 6, o = t & 63, g = o & ~7;
        float mg = 0.f, qg = 0.f;
#pragma unroll
        for (int j = 0; j < 8; ++j) { mg += EH[b][g + j]; qg += EQ[b][g + j]; }
        mg *= 0.125f; qg *= 0.125f;
        const float var = fmaxf(qg - mg*mg, 0.f);
        const float a = g2[o] / sqrtf(var + GN_EPS);
        ws[A2_OFF + b*64 + o] = a;
        ws[C2_OFF + b*64 + o] = be2[o] - mg*a;
    }
}

// ---------------- Kernel E: fused MFMA forward, wave-private pipeline (unchanged) ----------------
__global__ __launch_bounds__(256, 4) void pass3_kernel(
    const float* __restrict__ q, const float* __restrict__ kx,
    const int* __restrict__ idx, const int* __restrict__ mask,
    const float* __restrict__ w1,  const float* __restrict__ b1,
    const float* __restrict__ b2,  const float* __restrict__ ab1,
    const float* __restrict__ ab2,
    const float* __restrict__ cws, float* __restrict__ out)
{
    __shared__ __align__(16) _Float16 Xs[128 * 72];
    float* O = (float*)Xs;

    const int b = blockIdx.y;
    const int base = blockIdx.x * 128;
    const int tid = threadIdx.x;
    const int lane = tid & 63, wv = tid >> 6;
    const int colA = lane & 31;
    const int klo = (lane >> 5) * 8;
    const _Float16* WF = (const _Float16*)(cws + WF16_OFF);

    {
        const int p  = tid & 127;
        const int hh = tid >> 7;
        const int i  = base + p;
        const int mm = i >> 4;
        const int id = idx[(size_t)b*MK + i];
        const float ox = kx[(b*3 + 0)*Nn + id] - q[(b*3 + 0)*Mn + mm];
        const float oy = kx[(b*3 + 1)*Nn + id] - q[(b*3 + 1)*Mn + mm];
        const float oz = kx[(b*3 + 2)*Nn + id] - q[(b*3 + 2)*Mn + mm];
        const float d  = sqrtf(ox*ox + oy*oy + oz*oz);
        const float inv = 1.0f / fmaxf(d, 1e-12f);
        const float x0 = ox*inv, x1 = oy*inv, x2 = oz*inv, x3 = d;
        const float* a1 = cws + A1_OFF + (b << 6);
        const float* c1 = cws + C1_OFF + (b << 6);
#pragma unroll
        for (int u = 0; u < 16; ++u) {
            const int o0 = 32*hh + 2*u;
            const float4 wA = ((const float4*)w1)[o0];
            const float4 wB = ((const float4*)w1)[o0 + 1];
            float hA = fmaf(wA.x, x0, fmaf(wA.y, x1, fmaf(wA.z, x2, fmaf(wA.w, x3, b1[o0]))));
            float hB = fmaf(wB.x, x0, fmaf(wB.y, x1, fmaf(wB.z, x2, fmaf(wB.w, x3, b1[o0+1]))));
            hA = fmaxf(fmaf(a1[o0],     hA, c1[o0]),     0.f);
            hB = fmaxf(fmaf(a1[o0 + 1], hB, c1[o0 + 1]), 0.f);
            hf2 pk; pk[0] = (_Float16)hA; pk[1] = (_Float16)hB;
            *(hf2*)&Xs[p*72 + o0] = pk;
        }
    }
    const bool lvb = (lane < 32) && (mask[(size_t)b*MK + base + 32*wv + lane] != 0);
    const unsigned mb32 = (unsigned)__ballot(lvb);

    __syncthreads();

    const int rowA = 32*wv + colA;

    f32x16 pe0 = splat16(b2[colA]);
    f32x16 pe1 = splat16(b2[32 + colA]);
#pragma unroll
    for (int ks = 0; ks < 4; ++ks) {
        const int off = 16*ks + klo;
        hf8 a   = *(const hf8*)&Xs[rowA*72 + off];
        hf8 b0f = *(const hf8*)&WF[(colA)*64 + off];
        hf8 b1f = *(const hf8*)&WF[(32 + colA)*64 + off];
        pe0 = mfma16(a, b0f, pe0);
        pe1 = mfma16(a, b1f, pe1);
    }
#pragma unroll
    for (int r = 0; r < 16; ++r) {
        const int row = 32*wv + (r & 3) + 8*(r >> 2) + 4*(lane >> 5);
        Xs[row*72 + colA]      = (_Float16)pe0[r];
        Xs[row*72 + 32 + colA] = (_Float16)pe1[r];
    }

    f32x16 h0 = splat16(ab1[colA]);
    f32x16 h1 = splat16(ab1[32 + colA]);
#pragma unroll
    for (int ks = 0; ks < 4; ++ks) {
        const int off = 16*ks + klo;
        hf8 a   = *(const hf8*)&Xs[rowA*72 + off];
        hf8 b0f = *(const hf8*)&WF[4096 + (colA)*64 + off];
        hf8 b1f = *(const hf8*)&WF[4096 + (32 + colA)*64 + off];
        h0 = mfma16(a, b0f, h0);
        h1 = mfma16(a, b1f, h1);
    }
    {
        const float a2l = cws[A2_OFF + (b << 6) + colA];
        const float a2h = cws[A2_OFF + (b << 6) + 32 + colA];
        const float c2l = cws[C2_OFF + (b << 6) + colA];
        const float c2h = cws[C2_OFF + (b << 6) + 32 + colA];
#pragma unroll
        for (int r = 0; r < 16; ++r) {
            const int row = 32*wv + (r & 3) + 8*(r >> 2) + 4*(lane >> 5);
            Xs[row*72 + colA]      = (_Float16)fmaxf(fmaf(a2l, h0[r], c2l), 0.f);
            Xs[row*72 + 32 + colA] = (_Float16)fmaxf(fmaf(a2h, h1[r], c2h), 0.f);
        }
    }

    f32x16 l0 = splat16(ab2[colA]);
    f32x16 l1 = splat16(ab2[32 + colA]);
#pragma unroll
    for (int ks = 0; ks < 4; ++ks) {
        const int off = 16*ks + klo;
        hf8 a   = *(const hf8*)&Xs[rowA*72 + off];
        hf8 b0f = *(const hf8*)&WF[8192 + (colA)*64 + off];
        hf8 b1f = *(const hf8*)&WF[8192 + (32 + colA)*64 + off];
        l0 = mfma16(a, b0f, l0);
        l1 = mfma16(a, b1f, l1);
    }

    __syncthreads();

    {
        const int rbase4 = 4*(lane >> 5);
        auto softmax_tile = [&](const f32x16& lg, const f32x16& pe, int j) {
#pragma unroll
            for (int mh = 0; mh < 2; ++mh) {
                float lv[8];
                float mx = NEG_BIG;
#pragma unroll
                for (int rr = 0; rr < 8; ++rr) {
                    const int r = 8*mh + rr;
                    const int row = (r & 3) + 8*(r >> 2) + rbase4;
                    const float x = ((mb32 >> row) & 1u) ? lg[r] : NEG_BIG;
                    lv[rr] = x;
                    mx = fmaxf(mx, x);
                }
                mx = fmaxf(mx, __shfl_xor(mx, 32, 64));
                float se = 0.f, sw = 0.f;
#pragma unroll
                for (int rr = 0; rr < 8; ++rr) {
                    const float e = __expf(lv[rr] - mx);
                    se += e;
                    sw = fmaf(e, pe[8*mh + rr], sw);
                }
                se += __shfl_xor(se, 32, 64);
                sw += __shfl_xor(sw, 32, 64);
                if (lane < 32)
                    O[(32*j + lane)*9 + (2*wv + mh)] = sw / se;
            }
        };
        softmax_tile(l0, pe0, 0);
        softmax_tile(l1, pe1, 1);
    }
    __syncthreads();

    if (tid < 128) {
        const int o = tid >> 1, mq = (tid & 1) * 4;
        float4 v;
        v.x = O[o*9 + mq];     v.y = O[o*9 + mq + 1];
        v.z = O[o*9 + mq + 2]; v.w = O[o*9 + mq + 3];
        *(float4*)&out[((size_t)b*64 + o)*Mn + (base >> 4) + mq] = v;
    }
}

extern "C" void kernel_launch(void* const* d_in, const int* in_sizes, int n_in,
                              void* d_out, int out_size, void* d_ws, size_t ws_size,
                              hipStream_t stream) {
    (void)in_sizes; (void)n_in; (void)out_size; (void)ws_size;
    const float* q    = (const float*)d_in[0];
    const float* kx   = (const float*)d_in[1];
    const int*   idx  = (const int*)  d_in[2];
    const int*   mask = (const int*)  d_in[3];
    const float* w1   = (const float*)d_in[4];
    const float* b1   = (const float*)d_in[5];
    const float* g1   = (const float*)d_in[6];
    const float* be1  = (const float*)d_in[7];
    const float* w2   = (const float*)d_in[8];
    const float* b2   = (const float*)d_in[9];
    const float* aw1  = (const float*)d_in[10];
    const float* ab1  = (const float*)d_in[11];
    const float* g2   = (const float*)d_in[12];
    const float* be2  = (const float*)d_in[13];
    const float* aw2  = (const float*)d_in[14];
    const float* ab2  = (const float*)d_in[15];
    float* out = (float*)d_out;
    float* ws  = (float*)d_ws;

    stats1_kernel<<<dim3(G1, Bn), 256, 0, stream>>>(q, kx, idx, ws);
    prep1_kernel<<<1, 256, 0, stream>>>(ws, w1, b1, g1, be1, w2, b2, aw1, ab1, aw2, ws);
    pass2_kernel<<<dim3(G2, Bn), 256, 0, stream>>>(q, kx, idx, w1, b1, ws, ws);
    prep2_kernel<<<1, 256, 0, stream>>>(ws, g2, be2, ws);
    pass3_kernel<<<dim3(MK/128, Bn), 256, 0, stream>>>(
        q, kx, idx, mask, w1, b1, b2, ab1, ab2, ws, out);
}

// Round 5
// 246.548 us; speedup vs baseline: 7.4422x; 1.1723x over previous
//
#include <hip/hip_runtime.h>

// Problem constants
#define Bn 2
#define Mn 25000
#define Nn 100000
#define MK 400000           // Mn*Kn points per batch
#define GN_EPS 1e-5f
#define NEG_BIG (-3.402823466e+38f)

#define G1 512              // gatherx blocks per batch
#define G2 512              // pass2 blocks per batch

// ws layout (float offsets). No atomics; every region fully written before read.
#define A2_OFF   0        // [2][64]  gn2 scale
#define C2_OFF   128      // [2][64]  gn2 shift
#define BEFF_OFF 256      // [64]     at_w1@pe_b2 + at_b1
#define B1P_OFF  320      // [2][64]  folded gn1 bias: a1*b1 + c1
#define WF16_OFF 448      // 4*4096 f16: w2, aw1, aw2, Weff      (8192 floats)
#define W1F_OFF  8640     // [2][64][8] f16: a1-folded W1, K-padded (512 floats)
#define MSK_OFF  9152     // [2][25024] u16 packed mask          (25024 floats)
#define SP_OFF   34176    // [2][G1][16] gatherx moment partials (16384 floats)
#define YP_OFF   50560    // [2][G2][128] pass2 partials         (131072 floats)
#define XF_OFF   181632   // [2][MK][4] f16 cached local_pattern (1600000 floats)
// total: 1781632 floats ≈ 7.13 MB

typedef _Float16 hf8 __attribute__((ext_vector_type(8)));
typedef _Float16 hf4 __attribute__((ext_vector_type(4)));
typedef float f32x16 __attribute__((ext_vector_type(16)));

__device__ __forceinline__ f32x16 mfma16(hf8 a, hf8 b, f32x16 c) {
    return __builtin_amdgcn_mfma_f32_32x32x16_f16(a, b, c, 0, 0, 0);
}
__device__ __forceinline__ f32x16 splat16(float v) {
    f32x16 x;
#pragma unroll
    for (int r = 0; r < 16; ++r) x[r] = v;
    return x;
}
__device__ __forceinline__ hf8 zero8() {
    hf8 z;
#pragma unroll
    for (int j = 0; j < 8; ++j) z[j] = (_Float16)0.f;
    return z;
}
__device__ __forceinline__ float waveSum(float v) {
#pragma unroll
    for (int s = 32; s; s >>= 1) v += __shfl_down(v, s, 64);
    return v;
}
#define ROWFN(r, lane) (((r) & 3) + 8*((r) >> 2) + 4*((lane) >> 5))

// ---------------- Kernel A: gather once -> x-cache (f16) + packed mask + moments ----------------
__global__ __launch_bounds__(256) void gatherx_kernel(
    const float* __restrict__ q, const float* __restrict__ kx,
    const int* __restrict__ idx, const int* __restrict__ mask,
    float* __restrict__ ws)
{
    __shared__ float red[4][16];
    const int b = blockIdx.y;
    _Float16* xf = (_Float16*)(ws + XF_OFF);
    unsigned short* m16 = (unsigned short*)(ws + MSK_OFF) + (size_t)b*25024;
    float v[14];
#pragma unroll
    for (int j = 0; j < 14; ++j) v[j] = 0.f;

    for (int i = blockIdx.x*256 + threadIdx.x; i < MK; i += G1*256) {
        const int mm = i >> 4;
        const int id = idx[(size_t)b*MK + i];
        const float ox = kx[(b*3+0)*Nn + id] - q[(b*3+0)*Mn + mm];
        const float oy = kx[(b*3+1)*Nn + id] - q[(b*3+1)*Mn + mm];
        const float oz = kx[(b*3+2)*Nn + id] - q[(b*3+2)*Mn + mm];
        const float d  = sqrtf(ox*ox + oy*oy + oz*oz);
        const float inv = 1.0f / fmaxf(d, 1e-12f);
        const float x0 = ox*inv, x1 = oy*inv, x2 = oz*inv, x3 = d;

        hf4 pk; pk[0] = (_Float16)x0; pk[1] = (_Float16)x1;
        pk[2] = (_Float16)x2; pk[3] = (_Float16)x3;
        *(hf4*)&xf[((size_t)b*MK + i)*4] = pk;

        const unsigned long long mb = __ballot(mask[(size_t)b*MK + i] != 0);
        if ((threadIdx.x & 63) == 0)
            *(unsigned long long*)&m16[i >> 4] = mb;   // 4 m-groups per wave

        v[0] += x0; v[1] += x1; v[2] += x2; v[3] += x3;
        v[4] += x0*x0; v[5] += x0*x1; v[6] += x0*x2; v[7] += x0*x3;
        v[8] += x1*x1; v[9] += x1*x2; v[10] += x1*x3;
        v[11] += x2*x2; v[12] += x2*x3; v[13] += x3*x3;
    }
    const int lane = threadIdx.x & 63, wv = threadIdx.x >> 6;
#pragma unroll
    for (int j = 0; j < 14; ++j) v[j] = waveSum(v[j]);
    if (lane == 0) {
#pragma unroll
        for (int j = 0; j < 14; ++j) red[wv][j] = v[j];
    }
    __syncthreads();
    if (threadIdx.x < 14)
        ws[SP_OFF + ((size_t)b*G1 + blockIdx.x)*16 + threadIdx.x] =
            red[0][threadIdx.x] + red[1][threadIdx.x] + red[2][threadIdx.x] + red[3][threadIdx.x];
}

// ---------------- Kernel B: moments -> gn1 fold (W1', b1') + Weff/beff + f16 weights ----------------
__global__ void prep1_kernel(
    const float* __restrict__ ws_r,
    const float* __restrict__ w1, const float* __restrict__ b1,
    const float* __restrict__ g1, const float* __restrict__ be1,
    const float* __restrict__ w2, const float* __restrict__ pe_b2,
    const float* __restrict__ aw1, const float* __restrict__ ab1,
    const float* __restrict__ aw2,
    float* __restrict__ ws)
{
    __shared__ double S[2][14];
    __shared__ float Eh[2][64], Eq[2][64];
    __shared__ float WL[4096];
    const int t = threadIdx.x;

    if (t < 28) {
        const int b = t / 14, j = t % 14;
        const float* p = ws_r + SP_OFF + (size_t)b*G1*16 + j;
        double acc = 0.0;
        for (int g = 0; g < G1; g += 4)
            acc += (double)p[(g+0)*16] + (double)p[(g+1)*16]
                 + (double)p[(g+2)*16] + (double)p[(g+3)*16];
        S[b][j] = acc;
    }
    __syncthreads();

    if (t < 128) {
        const int b = t >> 6, o = t & 63;
        const double inv = 1.0 / (double)MK;
        double mu[4];
#pragma unroll
        for (int c = 0; c < 4; ++c) mu[c] = S[b][c] * inv;
        double m2[4][4];
        {
            const int map[4][4] = {{0,1,2,3},{1,4,5,6},{2,5,7,8},{3,6,8,9}};
#pragma unroll
            for (int c = 0; c < 4; ++c)
#pragma unroll
                for (int c2 = 0; c2 < 4; ++c2)
                    m2[c][c2] = S[b][4 + map[c][c2]] * inv;
        }
        double w[4];
#pragma unroll
        for (int c = 0; c < 4; ++c) w[c] = (double)w1[o*4 + c];
        double s = 0.0, qd = 0.0;
#pragma unroll
        for (int c = 0; c < 4; ++c) {
            s += w[c] * mu[c];
#pragma unroll
            for (int c2 = 0; c2 < 4; ++c2) qd += w[c]*w[c2]*m2[c][c2];
        }
        const double bb = (double)b1[o];
        Eh[b][o] = (float)(s + bb);
        Eq[b][o] = (float)(qd + 2.0*bb*s + bb*bb);
    }
    __syncthreads();
    if (t < 128) {
        const int b = t >> 6, o = t & 63, g = o & ~7;
        float mg = 0.f, qg = 0.f;
#pragma unroll
        for (int j = 0; j < 8; ++j) { mg += Eh[b][g + j]; qg += Eq[b][g + j]; }
        mg *= 0.125f; qg *= 0.125f;
        const float var = fmaxf(qg - mg*mg, 0.f);
        const float a = g1[o] / sqrtf(var + GN_EPS);
        const float c1v = be1[o] - mg*a;
        // folded: r1 = relu((a*W1) x + (a*b1 + c1))
        _Float16* W1F = (_Float16*)(ws + W1F_OFF);
        hf8 wrow;
#pragma unroll
        for (int c = 0; c < 4; ++c) wrow[c] = (_Float16)(a * w1[o*4 + c]);
#pragma unroll
        for (int c = 4; c < 8; ++c) wrow[c] = (_Float16)0.f;
        *(hf8*)&W1F[(b*64 + o)*8] = wrow;
        ws[B1P_OFF + b*64 + o] = fmaf(a, b1[o], c1v);
    }
    // Weff = at_w1 @ pe_w2 (LDS only) ; beff = at_w1 @ pe_b2 + at_b1
    for (int e = t; e < 4096; e += 256) {
        const int o = e >> 6, c = e & 63;
        float acc = 0.f;
        for (int d = 0; d < 64; ++d) acc = fmaf(aw1[o*64 + d], w2[d*64 + c], acc);
        WL[e] = acc;
    }
    if (t < 64) {
        float acc = ab1[t];
        for (int d = 0; d < 64; ++d) acc = fmaf(aw1[t*64 + d], pe_b2[d], acc);
        ws[BEFF_OFF + t] = acc;
    }
    __syncthreads();
    _Float16* WF = (_Float16*)(ws + WF16_OFF);
    for (int e = t; e < 4096; e += 256) {
        WF[e]         = (_Float16)w2[e];
        WF[4096 + e]  = (_Float16)aw1[e];
        WF[8192 + e]  = (_Float16)aw2[e];
        WF[12288 + e] = (_Float16)WL[e];
    }
}

// ---------------- Kernel C: Σy, Σy² (y = Weff@r1), all-MFMA, wave-private ----------------
__global__ __launch_bounds__(256, 4) void pass2_kernel(
    const float* __restrict__ cws, float* __restrict__ ws)
{
    __shared__ __align__(16) _Float16 Xs[4][32][72];
    const int b = blockIdx.y;
    const int tid = threadIdx.x, lane = tid & 63, wv = tid >> 6;
    const int colA = lane & 31;
    const int klo = (lane >> 5) * 8;
    const _Float16* xf  = (const _Float16*)(cws + XF_OFF);
    const _Float16* WFe = (const _Float16*)(cws + WF16_OFF) + 12288;  // Weff
    const _Float16* W1F = (const _Float16*)(cws + W1F_OFF);

    // register-held B fragments
    hf8 BW[2][4];
#pragma unroll
    for (int jc = 0; jc < 2; ++jc)
#pragma unroll
        for (int ks = 0; ks < 4; ++ks)
            BW[jc][ks] = *(const hf8*)&WFe[(jc*32 + colA)*64 + 16*ks + klo];
    hf8 BX[2];
    if (klo == 0) {
        BX[0] = *(const hf8*)&W1F[(b*64 +      colA)*8];
        BX[1] = *(const hf8*)&W1F[(b*64 + 32 + colA)*8];
    } else { BX[0] = zero8(); BX[1] = zero8(); }
    const float bias0 = cws[B1P_OFF + b*64 + colA];
    const float bias1 = cws[B1P_OFF + b*64 + 32 + colA];

    float sh[2] = {0.f, 0.f}, sq[2] = {0.f, 0.f};

    for (int base = blockIdx.x * 128; base < MK; base += G2 * 128) {
        const int pt0 = base + 32*wv;
        // x A-fragment straight from the cache
        hf8 ax = zero8();
        if (klo == 0) {
            hf4 xv = *(const hf4*)&xf[((size_t)b*MK + pt0 + colA)*4];
#pragma unroll
            for (int j = 0; j < 4; ++j) ax[j] = xv[j];
        }
        // r1-GEMM + relu epilogue -> wave-private LDS rows
        f32x16 r0 = splat16(bias0), r1t = splat16(bias1);
        r0  = mfma16(ax, BX[0], r0);
        r1t = mfma16(ax, BX[1], r1t);
#pragma unroll
        for (int r = 0; r < 16; ++r) {
            const int row = ROWFN(r, lane);
            Xs[wv][row][colA]      = (_Float16)fmaxf(r0[r],  0.f);
            Xs[wv][row][32 + colA] = (_Float16)fmaxf(r1t[r], 0.f);
        }
        // Weff-GEMM, accumulate stats from C directly
        hf8 A[4];
#pragma unroll
        for (int ks = 0; ks < 4; ++ks)
            A[ks] = *(const hf8*)&Xs[wv][colA][16*ks + klo];
#pragma unroll
        for (int jc = 0; jc < 2; ++jc) {
            f32x16 C = splat16(0.f);
#pragma unroll
            for (int ks = 0; ks < 4; ++ks) C = mfma16(A[ks], BW[jc][ks], C);
#pragma unroll
            for (int r = 0; r < 16; ++r) {
                const float vy = C[r];
                sh[jc] += vy;
                sq[jc] = fmaf(vy, vy, sq[jc]);
            }
        }
    }

#pragma unroll
    for (int jc = 0; jc < 2; ++jc) {
        sh[jc] += __shfl_xor(sh[jc], 32, 64);
        sq[jc] += __shfl_xor(sq[jc], 32, 64);
    }
    __syncthreads();
    float* red = (float*)Xs;   // [4][128]
    if (lane < 32) {
        red[wv*128 +      colA] = sh[0];
        red[wv*128 + 32 + colA] = sh[1];
        red[wv*128 + 64 + colA] = sq[0];
        red[wv*128 + 96 + colA] = sq[1];
    }
    __syncthreads();
    if (tid < 128) {
        const float v = red[tid] + red[128 + tid] + red[256 + tid] + red[384 + tid];
        ws[YP_OFF + ((size_t)b*G2 + blockIdx.x)*128 + tid] = v;
    }
}

// ---------------- Kernel D: reduce pass2 partials -> gn2 affine coeffs ----------------
__global__ void prep2_kernel(const float* __restrict__ ws_r,
                             const float* __restrict__ g2, const float* __restrict__ be2,
                             float* __restrict__ ws)
{
    __shared__ double sums[2][128];
    __shared__ float EH[2][64], EQ[2][64];
    const int t = threadIdx.x;   // 256
    {
        const int b = t >> 7, i = t & 127;
        const float* p = ws_r + YP_OFF + (size_t)b*G2*128 + i;
        double acc = 0.0;
        for (int g = 0; g < G2; g += 8) {
            acc += (double)p[(g+0)*128] + (double)p[(g+1)*128]
                 + (double)p[(g+2)*128] + (double)p[(g+3)*128]
                 + (double)p[(g+4)*128] + (double)p[(g+5)*128]
                 + (double)p[(g+6)*128] + (double)p[(g+7)*128];
        }
        sums[b][i] = acc;
    }
    __syncthreads();
    if (t < 128) {
        const int b = t >> 6, o = t & 63;
        const double invMK = 1.0 / (double)MK;
        const double my = sums[b][o] * invMK;
        const double qy = sums[b][64 + o] * invMK;
        const double beff = (double)ws_r[BEFF_OFF + o];
        EH[b][o] = (float)(my + beff);
        EQ[b][o] = (float)(qy + 2.0*beff*my + beff*beff);
    }
    __syncthreads();
    if (t < 128) {
        const int b = t >> 6, o = t & 63, g = o & ~7;
        float mg = 0.f, qg = 0.f;
#pragma unroll
        for (int j = 0; j < 8; ++j) { mg += EH[b][g + j]; qg += EQ[b][g + j]; }
        mg *= 0.125f; qg *= 0.125f;
        const float var = fmaxf(qg - mg*mg, 0.f);
        const float a = g2[o] / sqrtf(var + GN_EPS);
        ws[A2_OFF + b*64 + o] = a;
        ws[C2_OFF + b*64 + o] = be2[o] - mg*a;
    }
}

// ---------------- Kernel E: all-MFMA forward, wave-private, packed-mask ----------------
__global__ __launch_bounds__(256, 4) void pass3_kernel(
    const float* __restrict__ b2,  const float* __restrict__ ab1,
    const float* __restrict__ ab2,
    const float* __restrict__ cws, float* __restrict__ out)
{
    __shared__ __align__(16) _Float16 Xs[4][32][72];
    float* O = (float*)Xs;

    const int b = blockIdx.y;
    const int base = blockIdx.x * 128;     // 3125*128 == MK
    const int tid = threadIdx.x;
    const int lane = tid & 63, wv = tid >> 6;
    const int colA = lane & 31;
    const int klo = (lane >> 5) * 8;
    const int pt0 = base + 32*wv;

    const _Float16* xf  = (const _Float16*)(cws + XF_OFF);
    const _Float16* WF  = (const _Float16*)(cws + WF16_OFF);
    const _Float16* W1F = (const _Float16*)(cws + W1F_OFF);
    const unsigned mb32 = *(const unsigned*)((const unsigned short*)(cws + MSK_OFF)
                                             + (size_t)b*25024 + (pt0 >> 4));

    // ---- r1 via MFMA from cached x ----
    {
        hf8 ax = zero8();
        hf8 BX0, BX1;
        if (klo == 0) {
            hf4 xv = *(const hf4*)&xf[((size_t)b*MK + pt0 + colA)*4];
#pragma unroll
            for (int j = 0; j < 4; ++j) ax[j] = xv[j];
            BX0 = *(const hf8*)&W1F[(b*64 +      colA)*8];
            BX1 = *(const hf8*)&W1F[(b*64 + 32 + colA)*8];
        } else { BX0 = zero8(); BX1 = zero8(); }
        f32x16 r0 = splat16(cws[B1P_OFF + b*64 + colA]);
        f32x16 r1t = splat16(cws[B1P_OFF + b*64 + 32 + colA]);
        r0  = mfma16(ax, BX0, r0);
        r1t = mfma16(ax, BX1, r1t);
#pragma unroll
        for (int r = 0; r < 16; ++r) {
            const int row = ROWFN(r, lane);
            Xs[wv][row][colA]      = (_Float16)fmaxf(r0[r],  0.f);
            Xs[wv][row][32 + colA] = (_Float16)fmaxf(r1t[r], 0.f);
        }
    }

    // ---- GEMM1: pe = r1 @ w2^T + b2 ----
    f32x16 pe0 = splat16(b2[colA]);
    f32x16 pe1 = splat16(b2[32 + colA]);
#pragma unroll
    for (int ks = 0; ks < 4; ++ks) {
        const int off = 16*ks + klo;
        hf8 a   = *(const hf8*)&Xs[wv][colA][off];
        hf8 b0f = *(const hf8*)&WF[(colA)*64 + off];
        hf8 b1f = *(const hf8*)&WF[(32 + colA)*64 + off];
        pe0 = mfma16(a, b0f, pe0);
        pe1 = mfma16(a, b1f, pe1);
    }
#pragma unroll
    for (int r = 0; r < 16; ++r) {
        const int row = ROWFN(r, lane);
        Xs[wv][row][colA]      = (_Float16)pe0[r];
        Xs[wv][row][32 + colA] = (_Float16)pe1[r];
    }

    // ---- GEMM2: h2 = pe @ aw1^T + ab1, gn2 affine + relu ----
    f32x16 h0 = splat16(ab1[colA]);
    f32x16 h1 = splat16(ab1[32 + colA]);
#pragma unroll
    for (int ks = 0; ks < 4; ++ks) {
        const int off = 16*ks + klo;
        hf8 a   = *(const hf8*)&Xs[wv][colA][off];
        hf8 b0f = *(const hf8*)&WF[4096 + (colA)*64 + off];
        hf8 b1f = *(const hf8*)&WF[4096 + (32 + colA)*64 + off];
        h0 = mfma16(a, b0f, h0);
        h1 = mfma16(a, b1f, h1);
    }
    {
        const float a2l = cws[A2_OFF + (b << 6) + colA];
        const float a2h = cws[A2_OFF + (b << 6) + 32 + colA];
        const float c2l = cws[C2_OFF + (b << 6) + colA];
        const float c2h = cws[C2_OFF + (b << 6) + 32 + colA];
#pragma unroll
        for (int r = 0; r < 16; ++r) {
            const int row = ROWFN(r, lane);
            Xs[wv][row][colA]      = (_Float16)fmaxf(fmaf(a2l, h0[r], c2l), 0.f);
            Xs[wv][row][32 + colA] = (_Float16)fmaxf(fmaf(a2h, h1[r], c2h), 0.f);
        }
    }

    // ---- GEMM3: logits = r2 @ aw2^T + ab2 ----
    f32x16 l0 = splat16(ab2[colA]);
    f32x16 l1 = splat16(ab2[32 + colA]);
#pragma unroll
    for (int ks = 0; ks < 4; ++ks) {
        const int off = 16*ks + klo;
        hf8 a   = *(const hf8*)&Xs[wv][colA][off];
        hf8 b0f = *(const hf8*)&WF[8192 + (colA)*64 + off];
        hf8 b1f = *(const hf8*)&WF[8192 + (32 + colA)*64 + off];
        l0 = mfma16(a, b0f, l0);
        l1 = mfma16(a, b1f, l1);
    }

    __syncthreads();   // all Xs reads done; O may alias Xs

    // ---- masked softmax over K=16 + weighted pe sum ----
    {
        const int rbase4 = 4*(lane >> 5);
        auto softmax_tile = [&](const f32x16& lg, const f32x16& pe, int j) {
#pragma unroll
            for (int mh = 0; mh < 2; ++mh) {
                float lv[8];
                float mx = NEG_BIG;
#pragma unroll
                for (int rr = 0; rr < 8; ++rr) {
                    const int r = 8*mh + rr;
                    const int row = (r & 3) + 8*(r >> 2) + rbase4;
                    const float x = ((mb32 >> row) & 1u) ? lg[r] : NEG_BIG;
                    lv[rr] = x;
                    mx = fmaxf(mx, x);
                }
                mx = fmaxf(mx, __shfl_xor(mx, 32, 64));
                float se = 0.f, sw = 0.f;
#pragma unroll
                for (int rr = 0; rr < 8; ++rr) {
                    const float e = __expf(lv[rr] - mx);
                    se += e;
                    sw = fmaf(e, pe[8*mh + rr], sw);
                }
                se += __shfl_xor(se, 32, 64);
                sw += __shfl_xor(sw, 32, 64);
                if (lane < 32)
                    O[(32*j + lane)*9 + (2*wv + mh)] = sw / se;
            }
        };
        softmax_tile(l0, pe0, 0);
        softmax_tile(l1, pe1, 1);
    }
    __syncthreads();

    if (tid < 128) {
        const int o = tid >> 1, mq = (tid & 1) * 4;
        float4 v;
        v.x = O[o*9 + mq];     v.y = O[o*9 + mq + 1];
        v.z = O[o*9 + mq + 2]; v.w = O[o*9 + mq + 3];
        *(float4*)&out[((size_t)b*64 + o)*Mn + blockIdx.x*8 + mq] = v;
    }
}

extern "C" void kernel_launch(void* const* d_in, const int* in_sizes, int n_in,
                              void* d_out, int out_size, void* d_ws, size_t ws_size,
                              hipStream_t stream) {
    (void)in_sizes; (void)n_in; (void)out_size; (void)ws_size;
    const float* q    = (const float*)d_in[0];
    const float* kx   = (const float*)d_in[1];
    const int*   idx  = (const int*)  d_in[2];
    const int*   mask = (const int*)  d_in[3];
    const float* w1   = (const float*)d_in[4];
    const float* b1   = (const float*)d_in[5];
    const float* g1   = (const float*)d_in[6];
    const float* be1  = (const float*)d_in[7];
    const float* w2   = (const float*)d_in[8];
    const float* b2   = (const float*)d_in[9];
    const float* aw1  = (const float*)d_in[10];
    const float* ab1  = (const float*)d_in[11];
    const float* g2   = (const float*)d_in[12];
    const float* be2  = (const float*)d_in[13];
    const float* aw2  = (const float*)d_in[14];
    const float* ab2  = (const float*)d_in[15];
    float* out = (float*)d_out;
    float* ws  = (float*)d_ws;

    gatherx_kernel<<<dim3(G1, Bn), 256, 0, stream>>>(q, kx, idx, mask, ws);
    prep1_kernel<<<1, 256, 0, stream>>>(ws, w1, b1, g1, be1, w2, b2, aw1, ab1, aw2, ws);
    pass2_kernel<<<dim3(G2, Bn), 256, 0, stream>>>(ws, ws);
    prep2_kernel<<<1, 256, 0, stream>>>(ws, g2, be2, ws);
    pass3_kernel<<<dim3(MK/128, Bn), 256, 0, stream>>>(b2, ab1, ab2, ws, out);
}

// Round 7
// 245.980 us; speedup vs baseline: 7.4594x; 1.0023x over previous
//
#include <hip/hip_runtime.h>

// Problem constants
#define Bn 2
#define Mn 25000
#define Nn 100000
#define MK 400000           // Mn*Kn points per batch
#define GN_EPS 1e-5f
#define NEG_BIG (-3.402823466e+38f)

#define G1 512              // gatherx blocks per batch
#define G2 512              // pass2 blocks per batch

// ws layout (float offsets). No atomics; every region fully written before read.
#define BEFF_OFF 0        // [64]      at_w1@pe_b2 + at_b1
#define B1P_OFF  64       // [2][64]   folded gn1 bias
#define AB1P_OFF 192      // [2][64]   folded gn2 bias: a2*ab1 + c2
#define WF16_OFF 320      // 3*4096 f16: w2, aw2, Weff          (6144 floats)
#define AW1P_OFF 6464     // [2][4096] f16 folded a2*aw1        (4096 floats)
#define W1F_OFF  10560    // [2][64][8] f16 a1-folded W1, K-pad (512 floats)
#define MSK_OFF  11072    // [2][25024] u16 packed mask         (25024 floats)
#define SP_OFF   36096    // [2][G1][16] gatherx moment partials(16384 floats)
#define YP_OFF   52480    // [2][G2][128] pass2 partials        (131072 floats)
#define KXT_OFF  183552   // [2][Nn][4] f32 transposed kx       (800000 floats)
#define QT_OFF   983552   // [2][Mn][4] f32 transposed q        (200000 floats)
#define XF_OFF   1183552  // [2][MK][4] f16 cached local_pattern(1600000 floats)
// total: 2783552 floats ≈ 11.1 MB

typedef _Float16 hf8 __attribute__((ext_vector_type(8)));
typedef _Float16 hf4 __attribute__((ext_vector_type(4)));
typedef _Float16 hf2 __attribute__((ext_vector_type(2)));
typedef float f32x16 __attribute__((ext_vector_type(16)));

__device__ __forceinline__ f32x16 mfma16(hf8 a, hf8 b, f32x16 c) {
    return __builtin_amdgcn_mfma_f32_32x32x16_f16(a, b, c, 0, 0, 0);
}
__device__ __forceinline__ f32x16 splat16(float v) {
    f32x16 x;
#pragma unroll
    for (int r = 0; r < 16; ++r) x[r] = v;
    return x;
}
__device__ __forceinline__ hf8 zero8() {
    hf8 z;
#pragma unroll
    for (int j = 0; j < 8; ++j) z[j] = (_Float16)0.f;
    return z;
}
__device__ __forceinline__ hf2 pkcvt(float a, float b) {
    return __builtin_bit_cast(hf2, __builtin_amdgcn_cvt_pkrtz(a, b));
}
__device__ __forceinline__ hf2 pkrelu(hf2 v) {
    hf2 z; z[0] = (_Float16)0.f; z[1] = (_Float16)0.f;
    return __builtin_elementwise_max(v, z);
}
__device__ __forceinline__ float waveSum(float v) {
#pragma unroll
    for (int s = 32; s; s >>= 1) v += __shfl_down(v, s, 64);
    return v;
}
#define ROWFN(r, lane) (((r) & 3) + 8*((r) >> 2) + 4*((lane) >> 5))

// ---------------- Kernel 0: transpose kx/q to [n][4] ----------------
__global__ __launch_bounds__(256) void prep0_kernel(
    const float* __restrict__ q, const float* __restrict__ kx,
    float* __restrict__ ws)
{
    float4* kxt = (float4*)(ws + KXT_OFF);
    float4* qt  = (float4*)(ws + QT_OFF);
    for (int e = blockIdx.x*256 + threadIdx.x; e < 2*Nn; e += gridDim.x*256) {
        const int b = e / Nn, n = e % Nn;
        float4 v;
        v.x = kx[(b*3+0)*Nn + n]; v.y = kx[(b*3+1)*Nn + n];
        v.z = kx[(b*3+2)*Nn + n]; v.w = 0.f;
        kxt[e] = v;
    }
    for (int e = blockIdx.x*256 + threadIdx.x; e < 2*Mn; e += gridDim.x*256) {
        const int b = e / Mn, m = e % Mn;
        float4 v;
        v.x = q[(b*3+0)*Mn + m]; v.y = q[(b*3+1)*Mn + m];
        v.z = q[(b*3+2)*Mn + m]; v.w = 0.f;
        qt[e] = v;
    }
}

// ---------------- Kernel A: gather once -> x-cache (f16) + packed mask + moments ----------------
__global__ __launch_bounds__(256) void gatherx_kernel(
    const int* __restrict__ idx, const int* __restrict__ mask,
    float* __restrict__ ws)
{
    __shared__ float red[4][16];
    const int b = blockIdx.y;
    const float4* kxt = (const float4*)(ws + KXT_OFF) + (size_t)b*Nn;
    const float4* qt  = (const float4*)(ws + QT_OFF)  + (size_t)b*Mn;
    _Float16* xf = (_Float16*)(ws + XF_OFF);
    unsigned short* m16 = (unsigned short*)(ws + MSK_OFF) + (size_t)b*25024;
    float v[14];
#pragma unroll
    for (int j = 0; j < 14; ++j) v[j] = 0.f;

    for (int i = blockIdx.x*256 + threadIdx.x; i < MK; i += G1*256) {
        const int mm = i >> 4;
        const int id = idx[(size_t)b*MK + i];
        const float4 kv = kxt[id];
        const float4 qv = qt[mm];
        const float ox = kv.x - qv.x, oy = kv.y - qv.y, oz = kv.z - qv.z;
        const float d  = sqrtf(ox*ox + oy*oy + oz*oz);
        const float inv = 1.0f / fmaxf(d, 1e-12f);
        const float x0 = ox*inv, x1 = oy*inv, x2 = oz*inv, x3 = d;

        const hf2 lo = pkcvt(x0, x1);
        const hf2 hi = pkcvt(x2, x3);
        hf4 pk;
        pk[0] = lo[0]; pk[1] = lo[1]; pk[2] = hi[0]; pk[3] = hi[1];
        *(hf4*)&xf[((size_t)b*MK + i)*4] = pk;

        const unsigned long long mb = __ballot(mask[(size_t)b*MK + i] != 0);
        if ((threadIdx.x & 63) == 0)
            *(unsigned long long*)&m16[i >> 4] = mb;

        v[0] += x0; v[1] += x1; v[2] += x2; v[3] += x3;
        v[4] += x0*x0; v[5] += x0*x1; v[6] += x0*x2; v[7] += x0*x3;
        v[8] += x1*x1; v[9] += x1*x2; v[10] += x1*x3;
        v[11] += x2*x2; v[12] += x2*x3; v[13] += x3*x3;
    }
    const int lane = threadIdx.x & 63, wv = threadIdx.x >> 6;
#pragma unroll
    for (int j = 0; j < 14; ++j) v[j] = waveSum(v[j]);
    if (lane == 0) {
#pragma unroll
        for (int j = 0; j < 14; ++j) red[wv][j] = v[j];
    }
    __syncthreads();
    if (threadIdx.x < 14)
        ws[SP_OFF + ((size_t)b*G1 + blockIdx.x)*16 + threadIdx.x] =
            red[0][threadIdx.x] + red[1][threadIdx.x] + red[2][threadIdx.x] + red[3][threadIdx.x];
}

// ---------------- Kernel B: moments -> gn1 fold + Weff/beff + f16 weights ----------------
__global__ void prep1_kernel(
    const float* __restrict__ ws_r,
    const float* __restrict__ w1, const float* __restrict__ b1,
    const float* __restrict__ g1, const float* __restrict__ be1,
    const float* __restrict__ w2, const float* __restrict__ pe_b2,
    const float* __restrict__ aw1, const float* __restrict__ ab1,
    const float* __restrict__ aw2,
    float* __restrict__ ws)
{
    __shared__ double S[2][14];
    __shared__ float Eh[2][64], Eq[2][64];
    __shared__ float WL[4096];
    const int t = threadIdx.x;

    if (t < 28) {
        const int b = t / 14, j = t % 14;
        const float* p = ws_r + SP_OFF + (size_t)b*G1*16 + j;
        double acc = 0.0;
        for (int g = 0; g < G1; g += 4)
            acc += (double)p[(g+0)*16] + (double)p[(g+1)*16]
                 + (double)p[(g+2)*16] + (double)p[(g+3)*16];
        S[b][j] = acc;
    }
    __syncthreads();

    if (t < 128) {
        const int b = t >> 6, o = t & 63;
        const double inv = 1.0 / (double)MK;
        double mu[4];
#pragma unroll
        for (int c = 0; c < 4; ++c) mu[c] = S[b][c] * inv;
        double m2[4][4];
        {
            const int map[4][4] = {{0,1,2,3},{1,4,5,6},{2,5,7,8},{3,6,8,9}};
#pragma unroll
            for (int c = 0; c < 4; ++c)
#pragma unroll
                for (int c2 = 0; c2 < 4; ++c2)
                    m2[c][c2] = S[b][4 + map[c][c2]] * inv;
        }
        double w[4];
#pragma unroll
        for (int c = 0; c < 4; ++c) w[c] = (double)w1[o*4 + c];
        double s = 0.0, qd = 0.0;
#pragma unroll
        for (int c = 0; c < 4; ++c) {
            s += w[c] * mu[c];
#pragma unroll
            for (int c2 = 0; c2 < 4; ++c2) qd += w[c]*w[c2]*m2[c][c2];
        }
        const double bb = (double)b1[o];
        Eh[b][o] = (float)(s + bb);
        Eq[b][o] = (float)(qd + 2.0*bb*s + bb*bb);
    }
    __syncthreads();
    if (t < 128) {
        const int b = t >> 6, o = t & 63, g = o & ~7;
        float mg = 0.f, qg = 0.f;
#pragma unroll
        for (int j = 0; j < 8; ++j) { mg += Eh[b][g + j]; qg += Eq[b][g + j]; }
        mg *= 0.125f; qg *= 0.125f;
        const float var = fmaxf(qg - mg*mg, 0.f);
        const float a = g1[o] / sqrtf(var + GN_EPS);
        const float c1v = be1[o] - mg*a;
        _Float16* W1F = (_Float16*)(ws + W1F_OFF);
        hf8 wrow;
#pragma unroll
        for (int c = 0; c < 4; ++c) wrow[c] = (_Float16)(a * w1[o*4 + c]);
#pragma unroll
        for (int c = 4; c < 8; ++c) wrow[c] = (_Float16)0.f;
        *(hf8*)&W1F[(b*64 + o)*8] = wrow;
        ws[B1P_OFF + b*64 + o] = fmaf(a, b1[o], c1v);
    }
    for (int e = t; e < 4096; e += 256) {
        const int o = e >> 6, c = e & 63;
        float acc = 0.f;
        for (int d = 0; d < 64; ++d) acc = fmaf(aw1[o*64 + d], w2[d*64 + c], acc);
        WL[e] = acc;
    }
    if (t < 64) {
        float acc = ab1[t];
        for (int d = 0; d < 64; ++d) acc = fmaf(aw1[t*64 + d], pe_b2[d], acc);
        ws[BEFF_OFF + t] = acc;
    }
    __syncthreads();
    _Float16* WF = (_Float16*)(ws + WF16_OFF);
    for (int e = t; e < 4096; e += 256) {
        WF[e]        = (_Float16)w2[e];
        WF[4096 + e] = (_Float16)aw2[e];
        WF[8192 + e] = (_Float16)WL[e];
    }
}

// ---------------- Kernel C: Σy, Σy² (y = Weff@r1), all-MFMA, interleaved cols ----------------
__global__ __launch_bounds__(256, 4) void pass2_kernel(
    const float* __restrict__ cws, float* __restrict__ ws)
{
    __shared__ __align__(16) _Float16 Xs[4][32][72];
    const int b = blockIdx.y;
    const int tid = threadIdx.x, lane = tid & 63, wv = tid >> 6;
    const int colA = lane & 31;
    const int klo = (lane >> 5) * 8;
    const _Float16* xf  = (const _Float16*)(cws + XF_OFF);
    const _Float16* WFe = (const _Float16*)(cws + WF16_OFF) + 8192;  // Weff
    const _Float16* W1F = (const _Float16*)(cws + W1F_OFF);

    hf8 BW[2][4];
#pragma unroll
    for (int jc = 0; jc < 2; ++jc)
#pragma unroll
        for (int ks = 0; ks < 4; ++ks)
            BW[jc][ks] = *(const hf8*)&WFe[(2*colA + jc)*64 + 16*ks + klo];
    hf8 BX[2];
    if (klo == 0) {
        BX[0] = *(const hf8*)&W1F[(b*64 + 2*colA)*8];
        BX[1] = *(const hf8*)&W1F[(b*64 + 2*colA + 1)*8];
    } else { BX[0] = zero8(); BX[1] = zero8(); }
    const float bias0 = cws[B1P_OFF + b*64 + 2*colA];
    const float bias1 = cws[B1P_OFF + b*64 + 2*colA + 1];

    float sh[2] = {0.f, 0.f}, sq[2] = {0.f, 0.f};

    for (int base = blockIdx.x * 128; base < MK; base += G2 * 128) {
        const int pt0 = base + 32*wv;
        hf8 ax = zero8();
        if (klo == 0) {
            hf4 xv = *(const hf4*)&xf[((size_t)b*MK + pt0 + colA)*4];
#pragma unroll
            for (int j = 0; j < 4; ++j) ax[j] = xv[j];
        }
        f32x16 r0 = splat16(bias0), r1t = splat16(bias1);
        r0  = mfma16(ax, BX[0], r0);
        r1t = mfma16(ax, BX[1], r1t);
#pragma unroll
        for (int r = 0; r < 16; ++r) {
            const int row = ROWFN(r, lane);
            *(hf2*)&Xs[wv][row][2*colA] = pkrelu(pkcvt(r0[r], r1t[r]));
        }
        hf8 A[4];
#pragma unroll
        for (int ks = 0; ks < 4; ++ks)
            A[ks] = *(const hf8*)&Xs[wv][colA][16*ks + klo];
#pragma unroll
        for (int jc = 0; jc < 2; ++jc) {
            f32x16 C = splat16(0.f);
#pragma unroll
            for (int ks = 0; ks < 4; ++ks) C = mfma16(A[ks], BW[jc][ks], C);
#pragma unroll
            for (int r = 0; r < 16; ++r) {
                const float vy = C[r];
                sh[jc] += vy;
                sq[jc] = fmaf(vy, vy, sq[jc]);
            }
        }
    }

#pragma unroll
    for (int jc = 0; jc < 2; ++jc) {
        sh[jc] += __shfl_xor(sh[jc], 32, 64);
        sq[jc] += __shfl_xor(sq[jc], 32, 64);
    }
    __syncthreads();
    float* red = (float*)Xs;   // [4][128]
    if (lane < 32) {
#pragma unroll
        for (int jc = 0; jc < 2; ++jc) {
            red[wv*128 +      2*colA + jc] = sh[jc];
            red[wv*128 + 64 + 2*colA + jc] = sq[jc];
        }
    }
    __syncthreads();
    if (tid < 128) {
        const float v = red[tid] + red[128 + tid] + red[256 + tid] + red[384 + tid];
        ws[YP_OFF + ((size_t)b*G2 + blockIdx.x)*128 + tid] = v;
    }
}

// ---------------- Kernel D: reduce partials -> fold gn2 into aw1/ab1 ----------------
__global__ void prep2_kernel(const float* __restrict__ ws_r,
                             const float* __restrict__ g2, const float* __restrict__ be2,
                             const float* __restrict__ aw1, const float* __restrict__ ab1,
                             float* __restrict__ ws)
{
    __shared__ double sums[2][128];
    __shared__ float EH[2][64], EQ[2][64];
    __shared__ float A2s[2][64];
    const int t = threadIdx.x;   // 256
    {
        const int b = t >> 7, i = t & 127;
        const float* p = ws_r + YP_OFF + (size_t)b*G2*128 + i;
        double acc = 0.0;
        for (int g = 0; g < G2; g += 8) {
            acc += (double)p[(g+0)*128] + (double)p[(g+1)*128]
                 + (double)p[(g+2)*128] + (double)p[(g+3)*128]
                 + (double)p[(g+4)*128] + (double)p[(g+5)*128]
                 + (double)p[(g+6)*128] + (double)p[(g+7)*128];
        }
        sums[b][i] = acc;
    }
    __syncthreads();
    if (t < 128) {
        const int b = t >> 6, o = t & 63;
        const double invMK = 1.0 / (double)MK;
        const double my = sums[b][o] * invMK;
        const double qy = sums[b][64 + o] * invMK;
        const double beff = (double)ws_r[BEFF_OFF + o];
        EH[b][o] = (float)(my + beff);
        EQ[b][o] = (float)(qy + 2.0*beff*my + beff*beff);
    }
    __syncthreads();
    if (t < 128) {
        const int b = t >> 6, o = t & 63, g = o & ~7;
        float mg = 0.f, qg = 0.f;
#pragma unroll
        for (int j = 0; j < 8; ++j) { mg += EH[b][g + j]; qg += EQ[b][g + j]; }
        mg *= 0.125f; qg *= 0.125f;
        const float var = fmaxf(qg - mg*mg, 0.f);
        const float a = g2[o] / sqrtf(var + GN_EPS);
        A2s[b][o] = a;
        ws[AB1P_OFF + b*64 + o] = fmaf(a, ab1[o], be2[o] - mg*a);
    }
    __syncthreads();
    _Float16* AW1P = (_Float16*)(ws + AW1P_OFF);
    for (int e = t; e < 8192; e += 256) {
        const int b = e >> 12, oc = e & 4095, o = oc >> 6;
        AW1P[e] = (_Float16)(A2s[b][o] * aw1[oc]);
    }
}

// ---------------- Kernel E: all-MFMA forward, interleaved cols, packed epilogues ----------------
__global__ __launch_bounds__(256, 4) void pass3_kernel(
    const float* __restrict__ b2, const float* __restrict__ ab2,
    const float* __restrict__ cws, float* __restrict__ out)
{
    __shared__ __align__(16) _Float16 Xs[4][32][72];
    float* O = (float*)Xs;

    const int b = blockIdx.y;
    const int base = blockIdx.x * 128;     // 3125*128 == MK
    const int tid = threadIdx.x;
    const int lane = tid & 63, wv = tid >> 6;
    const int colA = lane & 31;
    const int klo = (lane >> 5) * 8;
    const int pt0 = base + 32*wv;

    const _Float16* xf   = (const _Float16*)(cws + XF_OFF);
    const _Float16* WF   = (const _Float16*)(cws + WF16_OFF);
    const _Float16* AW1P = (const _Float16*)(cws + AW1P_OFF) + (size_t)b*4096;
    const _Float16* W1F  = (const _Float16*)(cws + W1F_OFF);
    const unsigned mb32 = *(const unsigned*)((const unsigned short*)(cws + MSK_OFF)
                                             + (size_t)b*25024 + (pt0 >> 4));

    // ---- r1 via MFMA from cached x ----
    {
        hf8 ax = zero8();
        hf8 BX0, BX1;
        if (klo == 0) {
            hf4 xv = *(const hf4*)&xf[((size_t)b*MK + pt0 + colA)*4];
#pragma unroll
            for (int j = 0; j < 4; ++j) ax[j] = xv[j];
            BX0 = *(const hf8*)&W1F[(b*64 + 2*colA)*8];
            BX1 = *(const hf8*)&W1F[(b*64 + 2*colA + 1)*8];
        } else { BX0 = zero8(); BX1 = zero8(); }
        f32x16 r0  = splat16(cws[B1P_OFF + b*64 + 2*colA]);
        f32x16 r1t = splat16(cws[B1P_OFF + b*64 + 2*colA + 1]);
        r0  = mfma16(ax, BX0, r0);
        r1t = mfma16(ax, BX1, r1t);
#pragma unroll
        for (int r = 0; r < 16; ++r) {
            const int row = ROWFN(r, lane);
            *(hf2*)&Xs[wv][row][2*colA] = pkrelu(pkcvt(r0[r], r1t[r]));
        }
    }

    // ---- GEMM1: pe = r1 @ w2^T + b2 ----
    f32x16 pe0 = splat16(b2[2*colA]);
    f32x16 pe1 = splat16(b2[2*colA + 1]);
#pragma unroll
    for (int ks = 0; ks < 4; ++ks) {
        const int off = 16*ks + klo;
        hf8 a   = *(const hf8*)&Xs[wv][colA][off];
        hf8 b0f = *(const hf8*)&WF[(2*colA)*64 + off];
        hf8 b1f = *(const hf8*)&WF[(2*colA + 1)*64 + off];
        pe0 = mfma16(a, b0f, pe0);
        pe1 = mfma16(a, b1f, pe1);
    }
#pragma unroll
    for (int r = 0; r < 16; ++r) {
        const int row = ROWFN(r, lane);
        *(hf2*)&Xs[wv][row][2*colA] = pkcvt(pe0[r], pe1[r]);
    }

    // ---- GEMM2: r2 = relu(pe @ (a2*aw1)^T + ab1') ----
    f32x16 h0 = splat16(cws[AB1P_OFF + b*64 + 2*colA]);
    f32x16 h1 = splat16(cws[AB1P_OFF + b*64 + 2*colA + 1]);
#pragma unroll
    for (int ks = 0; ks < 4; ++ks) {
        const int off = 16*ks + klo;
        hf8 a   = *(const hf8*)&Xs[wv][colA][off];
        hf8 b0f = *(const hf8*)&AW1P[(2*colA)*64 + off];
        hf8 b1f = *(const hf8*)&AW1P[(2*colA + 1)*64 + off];
        h0 = mfma16(a, b0f, h0);
        h1 = mfma16(a, b1f, h1);
    }
#pragma unroll
    for (int r = 0; r < 16; ++r) {
        const int row = ROWFN(r, lane);
        *(hf2*)&Xs[wv][row][2*colA] = pkrelu(pkcvt(h0[r], h1[r]));
    }

    // ---- GEMM3: logits = r2 @ aw2^T + ab2 ----
    f32x16 l0 = splat16(ab2[2*colA]);
    f32x16 l1 = splat16(ab2[2*colA + 1]);
#pragma unroll
    for (int ks = 0; ks < 4; ++ks) {
        const int off = 16*ks + klo;
        hf8 a   = *(const hf8*)&Xs[wv][colA][off];
        hf8 b0f = *(const hf8*)&WF[4096 + (2*colA)*64 + off];
        hf8 b1f = *(const hf8*)&WF[4096 + (2*colA + 1)*64 + off];
        l0 = mfma16(a, b0f, l0);
        l1 = mfma16(a, b1f, l1);
    }

    __syncthreads();   // all Xs reads done; O may alias Xs

    // ---- masked softmax over K=16 + weighted pe sum ----
    {
        const int rbase4 = 4*(lane >> 5);
        auto softmax_tile = [&](const f32x16& lg, const f32x16& pe, int j) {
#pragma unroll
            for (int mh = 0; mh < 2; ++mh) {
                float lv[8];
                float mx = NEG_BIG;
#pragma unroll
                for (int rr = 0; rr < 8; ++rr) {
                    const int r = 8*mh + rr;
                    const int row = (r & 3) + 8*(r >> 2) + rbase4;
                    const float x = ((mb32 >> row) & 1u) ? lg[r] : NEG_BIG;
                    lv[rr] = x;
                    mx = fmaxf(mx, x);
                }
                mx = fmaxf(mx, __shfl_xor(mx, 32, 64));
                float se = 0.f, sw = 0.f;
#pragma unroll
                for (int rr = 0; rr < 8; ++rr) {
                    const float e = __expf(lv[rr] - mx);
                    se += e;
                    sw = fmaf(e, pe[8*mh + rr], sw);
                }
                se += __shfl_xor(se, 32, 64);
                sw += __shfl_xor(sw, 32, 64);
                if (lane < 32)
                    O[(2*lane + j)*9 + (2*wv + mh)] = sw / se;
            }
        };
        softmax_tile(l0, pe0, 0);
        softmax_tile(l1, pe1, 1);
    }
    __syncthreads();

    if (tid < 128) {
        const int o = tid >> 1, mq = (tid & 1) * 4;
        float4 v;
        v.x = O[o*9 + mq];     v.y = O[o*9 + mq + 1];
        v.z = O[o*9 + mq + 2]; v.w = O[o*9 + mq + 3];
        *(float4*)&out[((size_t)b*64 + o)*Mn + blockIdx.x*8 + mq] = v;
    }
}

extern "C" void kernel_launch(void* const* d_in, const int* in_sizes, int n_in,
                              void* d_out, int out_size, void* d_ws, size_t ws_size,
                              hipStream_t stream) {
    (void)in_sizes; (void)n_in; (void)out_size; (void)ws_size;
    const float* q    = (const float*)d_in[0];
    const float* kx   = (const float*)d_in[1];
    const int*   idx  = (const int*)  d_in[2];
    const int*   mask = (const int*)  d_in[3];
    const float* w1   = (const float*)d_in[4];
    const float* b1   = (const float*)d_in[5];
    const float* g1   = (const float*)d_in[6];
    const float* be1  = (const float*)d_in[7];
    const float* w2   = (const float*)d_in[8];
    const float* b2   = (const float*)d_in[9];
    const float* aw1  = (const float*)d_in[10];
    const float* ab1  = (const float*)d_in[11];
    const float* g2   = (const float*)d_in[12];
    const float* be2  = (const float*)d_in[13];
    const float* aw2  = (const float*)d_in[14];
    const float* ab2  = (const float*)d_in[15];
    float* out = (float*)d_out;
    float* ws  = (float*)d_ws;

    prep0_kernel<<<256, 256, 0, stream>>>(q, kx, ws);
    gatherx_kernel<<<dim3(G1, Bn), 256, 0, stream>>>(idx, mask, ws);
    prep1_kernel<<<1, 256, 0, stream>>>(ws, w1, b1, g1, be1, w2, b2, aw1, ab1, aw2, ws);
    pass2_kernel<<<dim3(G2, Bn), 256, 0, stream>>>(ws, ws);
    prep2_kernel<<<1, 256, 0, stream>>>(ws, g2, be2, aw1, ab1, ws);
    pass3_kernel<<<dim3(MK/128, Bn), 256, 0, stream>>>(b2, ab2, ws, out);
}

// Round 9
// 221.704 us; speedup vs baseline: 8.2761x; 1.1095x over previous
//
#include <hip/hip_runtime.h>

// Problem constants
#define Bn 2
#define Mn 25000
#define Nn 100000
#define MK 400000           // Mn*Kn points per batch
#define GN_EPS 1e-5f
#define NEG_BIG (-3.402823466e+38f)
#define LOG2E 1.44269504088896340736f

#define G1 512              // gatherx blocks per batch
#define G2 512              // pass2 blocks per batch

// ws layout (float offsets). No atomics; every region fully written before read.
#define BEFF_OFF 0        // [64]      at_w1@pe_b2 + at_b1
#define B1P_OFF  64       // [2][64]   folded gn1 bias
#define AB1P_OFF 192      // [2][64]   folded gn2 bias: a2*ab1 + c2
#define AB2L_OFF 320      // [64]      ab2 * log2e
#define WF16_OFF 384      // 3*4096 f16: w2, aw2*log2e, Weff    (6144 floats)
#define AW1P_OFF 6528     // [2][4096] f16 folded a2*aw1        (4096 floats)
#define W1F_OFF  10624    // [2][64][8] f16 a1-folded W1, K-pad (512 floats)
#define MSK_OFF  11136    // [2][25024] u16 packed mask         (25024 floats)
#define SP_OFF   36160    // [2][G1][16] gatherx moment partials(16384 floats)
#define YP_OFF   52544    // [2][G2][128] pass2 partials        (131072 floats)
#define YS_OFF   183616   // [2][128] doubles: reduced sums     (512 floats)
#define KXT_OFF  184128   // [2][Nn][4] f32 transposed kx       (800000 floats)
#define QT_OFF   984128   // [2][Mn][4] f32 transposed q        (200000 floats)
#define XF_OFF   1184128  // [2][MK][4] f16 cached local_pattern(1600000 floats)
// total: 2784128 floats ≈ 11.14 MB

typedef _Float16 hf8 __attribute__((ext_vector_type(8)));
typedef _Float16 hf4 __attribute__((ext_vector_type(4)));
typedef _Float16 hf2 __attribute__((ext_vector_type(2)));
typedef float f32x16 __attribute__((ext_vector_type(16)));

__device__ __forceinline__ f32x16 mfma16(hf8 a, hf8 b, f32x16 c) {
    return __builtin_amdgcn_mfma_f32_32x32x16_f16(a, b, c, 0, 0, 0);
}
__device__ __forceinline__ f32x16 splat16(float v) {
    f32x16 x;
#pragma unroll
    for (int r = 0; r < 16; ++r) x[r] = v;
    return x;
}
__device__ __forceinline__ hf8 zero8() {
    hf8 z;
#pragma unroll
    for (int j = 0; j < 8; ++j) z[j] = (_Float16)0.f;
    return z;
}
__device__ __forceinline__ hf2 pkcvt(float a, float b) {
    return __builtin_bit_cast(hf2, __builtin_amdgcn_cvt_pkrtz(a, b));
}
__device__ __forceinline__ hf2 pkrelu(hf2 v) {
    hf2 z; z[0] = (_Float16)0.f; z[1] = (_Float16)0.f;
    return __builtin_elementwise_max(v, z);
}
__device__ __forceinline__ float waveSum(float v) {
#pragma unroll
    for (int s = 32; s; s >>= 1) v += __shfl_down(v, s, 64);
    return v;
}
#define ROWFN(r, lane) (((r) & 3) + 8*((r) >> 2) + 4*((lane) >> 5))

// ---------------- Kernel 0: transpose kx/q to [n][4] ----------------
__global__ __launch_bounds__(256) void prep0_kernel(
    const float* __restrict__ q, const float* __restrict__ kx,
    float* __restrict__ ws)
{
    float4* kxt = (float4*)(ws + KXT_OFF);
    float4* qt  = (float4*)(ws + QT_OFF);
    for (int e = blockIdx.x*256 + threadIdx.x; e < 2*Nn; e += gridDim.x*256) {
        const int b = e / Nn, n = e % Nn;
        float4 v;
        v.x = kx[(b*3+0)*Nn + n]; v.y = kx[(b*3+1)*Nn + n];
        v.z = kx[(b*3+2)*Nn + n]; v.w = 0.f;
        kxt[e] = v;
    }
    for (int e = blockIdx.x*256 + threadIdx.x; e < 2*Mn; e += gridDim.x*256) {
        const int b = e / Mn, m = e % Mn;
        float4 v;
        v.x = q[(b*3+0)*Mn + m]; v.y = q[(b*3+1)*Mn + m];
        v.z = q[(b*3+2)*Mn + m]; v.w = 0.f;
        qt[e] = v;
    }
}

// ---------------- Kernel A: gather once -> x-cache (f16) + packed mask + moments ----------------
__global__ __launch_bounds__(256) void gatherx_kernel(
    const int* __restrict__ idx, const int* __restrict__ mask,
    float* __restrict__ ws)
{
    __shared__ float red[4][16];
    const int b = blockIdx.y;
    const float4* kxt = (const float4*)(ws + KXT_OFF) + (size_t)b*Nn;
    const float4* qt  = (const float4*)(ws + QT_OFF)  + (size_t)b*Mn;
    _Float16* xf = (_Float16*)(ws + XF_OFF);
    unsigned short* m16 = (unsigned short*)(ws + MSK_OFF) + (size_t)b*25024;
    float v[14];
#pragma unroll
    for (int j = 0; j < 14; ++j) v[j] = 0.f;

    for (int i = blockIdx.x*256 + threadIdx.x; i < MK; i += G1*256) {
        const int mm = i >> 4;
        const int id = idx[(size_t)b*MK + i];
        const float4 kv = kxt[id];
        const float4 qv = qt[mm];
        const float ox = kv.x - qv.x, oy = kv.y - qv.y, oz = kv.z - qv.z;
        const float d  = sqrtf(ox*ox + oy*oy + oz*oz);
        const float inv = 1.0f / fmaxf(d, 1e-12f);
        const float x0 = ox*inv, x1 = oy*inv, x2 = oz*inv, x3 = d;

        const hf2 lo = pkcvt(x0, x1);
        const hf2 hi = pkcvt(x2, x3);
        hf4 pk;
        pk[0] = lo[0]; pk[1] = lo[1]; pk[2] = hi[0]; pk[3] = hi[1];
        *(hf4*)&xf[((size_t)b*MK + i)*4] = pk;

        const unsigned long long mb = __ballot(mask[(size_t)b*MK + i] != 0);
        if ((threadIdx.x & 63) == 0)
            *(unsigned long long*)&m16[i >> 4] = mb;

        v[0] += x0; v[1] += x1; v[2] += x2; v[3] += x3;
        v[4] += x0*x0; v[5] += x0*x1; v[6] += x0*x2; v[7] += x0*x3;
        v[8] += x1*x1; v[9] += x1*x2; v[10] += x1*x3;
        v[11] += x2*x2; v[12] += x2*x3; v[13] += x3*x3;
    }
    const int lane = threadIdx.x & 63, wv = threadIdx.x >> 6;
#pragma unroll
    for (int j = 0; j < 14; ++j) v[j] = waveSum(v[j]);
    if (lane == 0) {
#pragma unroll
        for (int j = 0; j < 14; ++j) red[wv][j] = v[j];
    }
    __syncthreads();
    if (threadIdx.x < 14)
        ws[SP_OFF + ((size_t)b*G1 + blockIdx.x)*16 + threadIdx.x] =
            red[0][threadIdx.x] + red[1][threadIdx.x] + red[2][threadIdx.x] + red[3][threadIdx.x];
}

// ---------------- Kernel B: block0: moments -> gn1 fold + beff + ab2 prescale;
//                  blocks 1..16: Weff + f16 weight conversion (data-independent) ----------------
__global__ void prep1_kernel(
    const float* __restrict__ ws_r,
    const float* __restrict__ w1, const float* __restrict__ b1,
    const float* __restrict__ g1, const float* __restrict__ be1,
    const float* __restrict__ w2, const float* __restrict__ pe_b2,
    const float* __restrict__ aw1, const float* __restrict__ ab1,
    const float* __restrict__ aw2, const float* __restrict__ ab2,
    float* __restrict__ ws)
{
    const int t = threadIdx.x;
    _Float16* WF = (_Float16*)(ws + WF16_OFF);

    if (blockIdx.x > 0) {
        // one element per thread: 16 blocks x 256 threads = 4096 elements
        const int e = (blockIdx.x - 1)*256 + t;
        const int o = e >> 6, c = e & 63;
        WF[e]        = (_Float16)w2[e];
        WF[4096 + e] = (_Float16)(aw2[e] * LOG2E);
        float acc = 0.f;
        for (int d = 0; d < 64; ++d) acc = fmaf(aw1[o*64 + d], w2[d*64 + c], acc);
        WF[8192 + e] = (_Float16)acc;
        return;
    }

    __shared__ double S[2][14];
    __shared__ float Eh[2][64], Eq[2][64];

    if (t < 28) {
        const int b = t / 14, j = t % 14;
        const float* p = ws_r + SP_OFF + (size_t)b*G1*16 + j;
        double acc = 0.0;
        for (int g = 0; g < G1; g += 4)
            acc += (double)p[(g+0)*16] + (double)p[(g+1)*16]
                 + (double)p[(g+2)*16] + (double)p[(g+3)*16];
        S[b][j] = acc;
    }
    __syncthreads();

    if (t < 128) {
        const int b = t >> 6, o = t & 63;
        const double inv = 1.0 / (double)MK;
        double mu[4];
#pragma unroll
        for (int c = 0; c < 4; ++c) mu[c] = S[b][c] * inv;
        double m2[4][4];
        {
            const int map[4][4] = {{0,1,2,3},{1,4,5,6},{2,5,7,8},{3,6,8,9}};
#pragma unroll
            for (int c = 0; c < 4; ++c)
#pragma unroll
                for (int c2 = 0; c2 < 4; ++c2)
                    m2[c][c2] = S[b][4 + map[c][c2]] * inv;
        }
        double w[4];
#pragma unroll
        for (int c = 0; c < 4; ++c) w[c] = (double)w1[o*4 + c];
        double s = 0.0, qd = 0.0;
#pragma unroll
        for (int c = 0; c < 4; ++c) {
            s += w[c] * mu[c];
#pragma unroll
            for (int c2 = 0; c2 < 4; ++c2) qd += w[c]*w[c2]*m2[c][c2];
        }
        const double bb = (double)b1[o];
        Eh[b][o] = (float)(s + bb);
        Eq[b][o] = (float)(qd + 2.0*bb*s + bb*bb);
    }
    __syncthreads();
    if (t < 128) {
        const int b = t >> 6, o = t & 63, g = o & ~7;
        float mg = 0.f, qg = 0.f;
#pragma unroll
        for (int j = 0; j < 8; ++j) { mg += Eh[b][g + j]; qg += Eq[b][g + j]; }
        mg *= 0.125f; qg *= 0.125f;
        const float var = fmaxf(qg - mg*mg, 0.f);
        const float a = g1[o] / sqrtf(var + GN_EPS);
        const float c1v = be1[o] - mg*a;
        _Float16* W1F = (_Float16*)(ws + W1F_OFF);
        hf8 wrow;
#pragma unroll
        for (int c = 0; c < 4; ++c) wrow[c] = (_Float16)(a * w1[o*4 + c]);
#pragma unroll
        for (int c = 4; c < 8; ++c) wrow[c] = (_Float16)0.f;
        *(hf8*)&W1F[(b*64 + o)*8] = wrow;
        ws[B1P_OFF + b*64 + o] = fmaf(a, b1[o], c1v);
    }
    if (t < 64) {
        float acc = ab1[t];
        for (int d = 0; d < 64; ++d) acc = fmaf(aw1[t*64 + d], pe_b2[d], acc);
        ws[BEFF_OFF + t] = acc;
    } else if (t < 128) {
        ws[AB2L_OFF + (t - 64)] = ab2[t - 64] * LOG2E;
    }
}

// ---------------- Kernel C: Σy, Σy² (y = Weff@r1), all-MFMA, interleaved cols ----------------
__global__ __launch_bounds__(256, 4) void pass2_kernel(
    const float* __restrict__ cws, float* __restrict__ ws)
{
    __shared__ __align__(16) _Float16 Xs[4][32][72];
    const int b = blockIdx.y;
    const int tid = threadIdx.x, lane = tid & 63, wv = tid >> 6;
    const int colA = lane & 31;
    const int klo = (lane >> 5) * 8;
    const _Float16* xf  = (const _Float16*)(cws + XF_OFF);
    const _Float16* WFe = (const _Float16*)(cws + WF16_OFF) + 8192;  // Weff
    const _Float16* W1F = (const _Float16*)(cws + W1F_OFF);

    hf8 BW[2][4];
#pragma unroll
    for (int jc = 0; jc < 2; ++jc)
#pragma unroll
        for (int ks = 0; ks < 4; ++ks)
            BW[jc][ks] = *(const hf8*)&WFe[(2*colA + jc)*64 + 16*ks + klo];
    hf8 BX[2];
    if (klo == 0) {
        BX[0] = *(const hf8*)&W1F[(b*64 + 2*colA)*8];
        BX[1] = *(const hf8*)&W1F[(b*64 + 2*colA + 1)*8];
    } else { BX[0] = zero8(); BX[1] = zero8(); }
    const float bias0 = cws[B1P_OFF + b*64 + 2*colA];
    const float bias1 = cws[B1P_OFF + b*64 + 2*colA + 1];

    float sh[2] = {0.f, 0.f}, sq[2] = {0.f, 0.f};

    for (int base = blockIdx.x * 128; base < MK; base += G2 * 128) {
        const int pt0 = base + 32*wv;
        hf8 ax = zero8();
        if (klo == 0) {
            hf4 xv = *(const hf4*)&xf[((size_t)b*MK + pt0 + colA)*4];
#pragma unroll
            for (int j = 0; j < 4; ++j) ax[j] = xv[j];
        }
        f32x16 r0 = splat16(bias0), r1t = splat16(bias1);
        r0  = mfma16(ax, BX[0], r0);
        r1t = mfma16(ax, BX[1], r1t);
#pragma unroll
        for (int r = 0; r < 16; ++r) {
            const int row = ROWFN(r, lane);
            *(hf2*)&Xs[wv][row][2*colA] = pkrelu(pkcvt(r0[r], r1t[r]));
        }
        hf8 A[4];
#pragma unroll
        for (int ks = 0; ks < 4; ++ks)
            A[ks] = *(const hf8*)&Xs[wv][colA][16*ks + klo];
#pragma unroll
        for (int jc = 0; jc < 2; ++jc) {
            f32x16 C = splat16(0.f);
#pragma unroll
            for (int ks = 0; ks < 4; ++ks) C = mfma16(A[ks], BW[jc][ks], C);
#pragma unroll
            for (int r = 0; r < 16; ++r) {
                const float vy = C[r];
                sh[jc] += vy;
                sq[jc] = fmaf(vy, vy, sq[jc]);
            }
        }
    }

#pragma unroll
    for (int jc = 0; jc < 2; ++jc) {
        sh[jc] += __shfl_xor(sh[jc], 32, 64);
        sq[jc] += __shfl_xor(sq[jc], 32, 64);
    }
    __syncthreads();
    float* red = (float*)Xs;   // [4][128]
    if (lane < 32) {
#pragma unroll
        for (int jc = 0; jc < 2; ++jc) {
            red[wv*128 +      2*colA + jc] = sh[jc];
            red[wv*128 + 64 + 2*colA + jc] = sq[jc];
        }
    }
    __syncthreads();
    if (tid < 128) {
        const float v = red[tid] + red[128 + tid] + red[256 + tid] + red[384 + tid];
        ws[YP_OFF + ((size_t)b*G2 + blockIdx.x)*128 + tid] = v;
    }
}

// ---------------- Kernel D1: parallel reduce of pass2 partials (one block per output) ----------------
__global__ __launch_bounds__(64) void prep2a_kernel(
    const float* __restrict__ ws_r, float* __restrict__ ws)
{
    const int o2 = blockIdx.x;            // [0,256): b = o2>>7, i = o2&127
    const int b = o2 >> 7, i = o2 & 127;
    const float* p = ws_r + YP_OFF + (size_t)b*G2*128 + i;
    double acc = 0.0;
    for (int g = threadIdx.x; g < G2; g += 64) acc += (double)p[(size_t)g*128];
#pragma unroll
    for (int s = 32; s; s >>= 1) acc += __shfl_down(acc, s, 64);
    if (threadIdx.x == 0) ((double*)(ws + YS_OFF))[o2] = acc;
}

// ---------------- Kernel D2: gn2 coeffs + fold into aw1/ab1 ----------------
__global__ void prep2b_kernel(const float* __restrict__ ws_r,
                              const float* __restrict__ g2, const float* __restrict__ be2,
                              const float* __restrict__ aw1, const float* __restrict__ ab1,
                              float* __restrict__ ws)
{
    __shared__ float EH[2][64], EQ[2][64];
    __shared__ float A2s[2][64];
    const int t = threadIdx.x;   // 256
    const double* YS = (const double*)(ws_r + YS_OFF);
    if (t < 128) {
        const int b = t >> 6, o = t & 63;
        const double invMK = 1.0 / (double)MK;
        const double my = YS[b*128 + o] * invMK;
        const double qy = YS[b*128 + 64 + o] * invMK;
        const double beff = (double)ws_r[BEFF_OFF + o];
        EH[b][o] = (float)(my + beff);
        EQ[b][o] = (float)(qy + 2.0*beff*my + beff*beff);
    }
    __syncthreads();
    if (t < 128) {
        const int b = t >> 6, o = t & 63, g = o & ~7;
        float mg = 0.f, qg = 0.f;
#pragma unroll
        for (int j = 0; j < 8; ++j) { mg += EH[b][g + j]; qg += EQ[b][g + j]; }
        mg *= 0.125f; qg *= 0.125f;
        const float var = fmaxf(qg - mg*mg, 0.f);
        const float a = g2[o] / sqrtf(var + GN_EPS);
        A2s[b][o] = a;
        ws[AB1P_OFF + b*64 + o] = fmaf(a, ab1[o], be2[o] - mg*a);
    }
    __syncthreads();
    _Float16* AW1P = (_Float16*)(ws + AW1P_OFF);
    for (int e = t; e < 8192; e += 256) {
        const int b = e >> 12, oc = e & 4095, o = oc >> 6;
        AW1P[e] = (_Float16)(A2s[b][o] * aw1[oc]);
    }
}

// ---------------- Kernel E: all-MFMA forward; mask via rank-1 MFMA bias; exp2 softmax ----------------
__global__ __launch_bounds__(256, 4) void pass3_kernel(
    const float* __restrict__ b2,
    const float* __restrict__ cws, float* __restrict__ out)
{
    __shared__ __align__(16) _Float16 Xs[4][32][72];
    float* O = (float*)Xs;

    const int b = blockIdx.y;
    const int base = blockIdx.x * 128;     // 3125*128 == MK
    const int tid = threadIdx.x;
    const int lane = tid & 63, wv = tid >> 6;
    const int colA = lane & 31;
    const int klo = (lane >> 5) * 8;
    const int pt0 = base + 32*wv;

    const _Float16* xf   = (const _Float16*)(cws + XF_OFF);
    const _Float16* WF   = (const _Float16*)(cws + WF16_OFF);
    const _Float16* AW1P = (const _Float16*)(cws + AW1P_OFF) + (size_t)b*4096;
    const _Float16* W1F  = (const _Float16*)(cws + W1F_OFF);
    const unsigned mb32 = *(const unsigned*)((const unsigned short*)(cws + MSK_OFF)
                                             + (size_t)b*25024 + (pt0 >> 4));
    const unsigned mbs = __builtin_amdgcn_readfirstlane(mb32);

    // ---- r1 via MFMA from cached x ----
    {
        hf8 ax = zero8();
        hf8 BX0, BX1;
        if (klo == 0) {
            hf4 xv = *(const hf4*)&xf[((size_t)b*MK + pt0 + colA)*4];
#pragma unroll
            for (int j = 0; j < 4; ++j) ax[j] = xv[j];
            BX0 = *(const hf8*)&W1F[(b*64 + 2*colA)*8];
            BX1 = *(const hf8*)&W1F[(b*64 + 2*colA + 1)*8];
        } else { BX0 = zero8(); BX1 = zero8(); }
        f32x16 r0  = splat16(cws[B1P_OFF + b*64 + 2*colA]);
        f32x16 r1t = splat16(cws[B1P_OFF + b*64 + 2*colA + 1]);
        r0  = mfma16(ax, BX0, r0);
        r1t = mfma16(ax, BX1, r1t);
#pragma unroll
        for (int r = 0; r < 16; ++r) {
            const int row = ROWFN(r, lane);
            *(hf2*)&Xs[wv][row][2*colA] = pkrelu(pkcvt(r0[r], r1t[r]));
        }
    }
    // mask bias into pad cols [64..71]: FULL 8-half write so the later a5
    // fragment reads no uninitialized LDS (0 x NaN = NaN inside MFMA!)
    if (lane < 32) {
        hf8 pad = zero8();
        pad[0] = ((mb32 >> lane) & 1u) ? (_Float16)0.f : (_Float16)(-60000.f);
        *(hf8*)&Xs[wv][lane][64] = pad;
    }

    // ---- GEMM1: pe = r1 @ w2^T + b2 ----
    f32x16 pe0 = splat16(b2[2*colA]);
    f32x16 pe1 = splat16(b2[2*colA + 1]);
#pragma unroll
    for (int ks = 0; ks < 4; ++ks) {
        const int off = 16*ks + klo;
        hf8 a   = *(const hf8*)&Xs[wv][colA][off];
        hf8 b0f = *(const hf8*)&WF[(2*colA)*64 + off];
        hf8 b1f = *(const hf8*)&WF[(2*colA + 1)*64 + off];
        pe0 = mfma16(a, b0f, pe0);
        pe1 = mfma16(a, b1f, pe1);
    }
#pragma unroll
    for (int r = 0; r < 16; ++r) {
        const int row = ROWFN(r, lane);
        *(hf2*)&Xs[wv][row][2*colA] = pkcvt(pe0[r], pe1[r]);
    }

    // ---- GEMM2: r2 = relu(pe @ (a2*aw1)^T + ab1') ----
    f32x16 h0 = splat16(cws[AB1P_OFF + b*64 + 2*colA]);
    f32x16 h1 = splat16(cws[AB1P_OFF + b*64 + 2*colA + 1]);
#pragma unroll
    for (int ks = 0; ks < 4; ++ks) {
        const int off = 16*ks + klo;
        hf8 a   = *(const hf8*)&Xs[wv][colA][off];
        hf8 b0f = *(const hf8*)&AW1P[(2*colA)*64 + off];
        hf8 b1f = *(const hf8*)&AW1P[(2*colA + 1)*64 + off];
        h0 = mfma16(a, b0f, h0);
        h1 = mfma16(a, b1f, h1);
    }
#pragma unroll
    for (int r = 0; r < 16; ++r) {
        const int row = ROWFN(r, lane);
        *(hf2*)&Xs[wv][row][2*colA] = pkrelu(pkcvt(h0[r], h1[r]));
    }

    // ---- GEMM3: logits(log2-domain) = r2 @ (aw2*log2e)^T + ab2*log2e + maskbias ----
    f32x16 l0 = splat16(cws[AB2L_OFF + 2*colA]);
    f32x16 l1 = splat16(cws[AB2L_OFF + 2*colA + 1]);
#pragma unroll
    for (int ks = 0; ks < 4; ++ks) {
        const int off = 16*ks + klo;
        hf8 a   = *(const hf8*)&Xs[wv][colA][off];
        hf8 b0f = *(const hf8*)&WF[4096 + (2*colA)*64 + off];
        hf8 b1f = *(const hf8*)&WF[4096 + (2*colA + 1)*64 + off];
        l0 = mfma16(a, b0f, l0);
        l1 = mfma16(a, b1f, l1);
    }
    {   // rank-1 mask-bias update: adds bias[m] to every channel
        hf8 a5 = zero8(), b5 = zero8();
        if (klo == 0) {
            a5 = *(const hf8*)&Xs[wv][colA][64];   // [bias, 0 x 7]
            b5[0] = (_Float16)1.f;                 // selects only k=64
        }
        l0 = mfma16(a5, b5, l0);
        l1 = mfma16(a5, b5, l1);
    }

    __syncthreads();   // all Xs reads done; O may alias Xs

    // ---- softmax over K=16 (exp2 domain) + weighted pe sum ----
    {
        auto softmax_tile = [&](const f32x16& lg, const f32x16& pe, int j) {
#pragma unroll
            for (int mh = 0; mh < 2; ++mh) {
                float mx = lg[8*mh];
#pragma unroll
                for (int rr = 1; rr < 8; ++rr) mx = fmaxf(mx, lg[8*mh + rr]);
                mx = fmaxf(mx, __shfl_xor(mx, 32, 64));
                float se, sw = 0.f;
                if (((mbs >> (16*mh)) & 0xFFFFu) != 0u) {
                    se = 0.f;
#pragma unroll
                    for (int rr = 0; rr < 8; ++rr) {
                        const float e = exp2f(lg[8*mh + rr] - mx);
                        se += e;
                        sw = fmaf(e, pe[8*mh + rr], sw);
                    }
                } else {
                    // fully-masked m-group: exact uniform softmax (mean of pe)
                    se = 8.f;
#pragma unroll
                    for (int rr = 0; rr < 8; ++rr) sw += pe[8*mh + rr];
                }
                se += __shfl_xor(se, 32, 64);
                sw += __shfl_xor(sw, 32, 64);
                if (lane < 32)
                    O[(2*lane + j)*9 + (2*wv + mh)] = sw * __builtin_amdgcn_rcpf(se);
            }
        };
        softmax_tile(l0, pe0, 0);
        softmax_tile(l1, pe1, 1);
    }
    __syncthreads();

    if (tid < 128) {
        const int o = tid >> 1, mq = (tid & 1) * 4;
        float4 v;
        v.x = O[o*9 + mq];     v.y = O[o*9 + mq + 1];
        v.z = O[o*9 + mq + 2]; v.w = O[o*9 + mq + 3];
        *(float4*)&out[((size_t)b*64 + o)*Mn + blockIdx.x*8 + mq] = v;
    }
}

extern "C" void kernel_launch(void* const* d_in, const int* in_sizes, int n_in,
                              void* d_out, int out_size, void* d_ws, size_t ws_size,
                              hipStream_t stream) {
    (void)in_sizes; (void)n_in; (void)out_size; (void)ws_size;
    const float* q    = (const float*)d_in[0];
    const float* kx   = (const float*)d_in[1];
    const int*   idx  = (const int*)  d_in[2];
    const int*   mask = (const int*)  d_in[3];
    const float* w1   = (const float*)d_in[4];
    const float* b1   = (const float*)d_in[5];
    const float* g1   = (const float*)d_in[6];
    const float* be1  = (const float*)d_in[7];
    const float* w2   = (const float*)d_in[8];
    const float* b2   = (const float*)d_in[9];
    const float* aw1  = (const float*)d_in[10];
    const float* ab1  = (const float*)d_in[11];
    const float* g2   = (const float*)d_in[12];
    const float* be2  = (const float*)d_in[13];
    const float* aw2  = (const float*)d_in[14];
    const float* ab2  = (const float*)d_in[15];
    float* out = (float*)d_out;
    float* ws  = (float*)d_ws;

    prep0_kernel<<<256, 256, 0, stream>>>(q, kx, ws);
    gatherx_kernel<<<dim3(G1, Bn), 256, 0, stream>>>(idx, mask, ws);
    prep1_kernel<<<17, 256, 0, stream>>>(ws, w1, b1, g1, be1, w2, b2, aw1, ab1, aw2, ab2, ws);
    pass2_kernel<<<dim3(G2, Bn), 256, 0, stream>>>(ws, ws);
    prep2a_kernel<<<256, 64, 0, stream>>>(ws, ws);
    prep2b_kernel<<<1, 256, 0, stream>>>(ws, g2, be2, aw1, ab1, ws);
    pass3_kernel<<<dim3(MK/128, Bn), 256, 0, stream>>>(b2, ws, out);
}

// Round 10
// 193.559 us; speedup vs baseline: 9.4796x; 1.1454x over previous
//
#include <hip/hip_runtime.h>

// Problem constants
#define Bn 2
#define Mn 25000
#define Nn 100000
#define MK 400000           // Mn*Kn points per batch
#define GN_EPS 1e-5f
#define NEG_BIG (-3.402823466e+38f)
#define LOG2E 1.44269504088896340736f

#define G1 512              // gatherx blocks per batch
#define G2 512              // pass2 blocks per batch

// ws layout (float offsets). No atomics; every region fully written before read.
#define BEFF_OFF 0        // [64]      at_w1@pe_b2 + at_b1
#define B1P_OFF  64       // [2][64]   folded gn1 bias
#define AB1P_OFF 192      // [2][64]   folded gn2 bias: a2*ab1 + c2
#define AB2L_OFF 320      // [64]      ab2 * log2e
#define WF16_OFF 384      // 3*4096 f16: w2, aw2*log2e, Weff    (6144 floats)
#define AW1P_OFF 6528     // [2][4096] f16 folded a2*aw1        (4096 floats)
#define W1F_OFF  10624    // [2][64][8] f16 a1-folded W1, K-pad (512 floats)
#define MSK_OFF  11136    // [2][25024] u16 packed mask         (25024 floats)
#define SP_OFF   36160    // [2][G1][16] gatherx moment partials(16384 floats)
#define YP_OFF   52544    // [2][G2][128] pass2 partials        (131072 floats)
#define YS_OFF   183616   // [2][128] doubles: reduced sums     (512 floats)
#define KXT_OFF  184128   // [2][Nn][4] f32 transposed kx       (800000 floats)
#define QT_OFF   984128   // [2][Mn][4] f32 transposed q        (200000 floats)
#define XF_OFF   1184128  // [2][MK][4] f16 cached local_pattern(1600000 floats)
// total: 2784128 floats ≈ 11.14 MB

typedef _Float16 hf8 __attribute__((ext_vector_type(8)));
typedef _Float16 hf4 __attribute__((ext_vector_type(4)));
typedef _Float16 hf2 __attribute__((ext_vector_type(2)));
typedef float f32x16 __attribute__((ext_vector_type(16)));

__device__ __forceinline__ f32x16 mfma16(hf8 a, hf8 b, f32x16 c) {
    return __builtin_amdgcn_mfma_f32_32x32x16_f16(a, b, c, 0, 0, 0);
}
__device__ __forceinline__ f32x16 splat16(float v) {
    f32x16 x;
#pragma unroll
    for (int r = 0; r < 16; ++r) x[r] = v;
    return x;
}
__device__ __forceinline__ hf8 zero8() {
    hf8 z;
#pragma unroll
    for (int j = 0; j < 8; ++j) z[j] = (_Float16)0.f;
    return z;
}
__device__ __forceinline__ hf2 pkcvt(float a, float b) {
    return __builtin_bit_cast(hf2, __builtin_amdgcn_cvt_pkrtz(a, b));
}
__device__ __forceinline__ hf2 pkrelu(hf2 v) {
    hf2 z; z[0] = (_Float16)0.f; z[1] = (_Float16)0.f;
    return __builtin_elementwise_max(v, z);
}
__device__ __forceinline__ float waveSum(float v) {
#pragma unroll
    for (int s = 32; s; s >>= 1) v += __shfl_down(v, s, 64);
    return v;
}
#define ROWFN(r, lane) (((r) & 3) + 8*((r) >> 2) + 4*((lane) >> 5))

// ---------------- Kernel 0: transpose kx/q to [n][4] ----------------
__global__ __launch_bounds__(256) void prep0_kernel(
    const float* __restrict__ q, const float* __restrict__ kx,
    float* __restrict__ ws)
{
    float4* kxt = (float4*)(ws + KXT_OFF);
    float4* qt  = (float4*)(ws + QT_OFF);
    for (int e = blockIdx.x*256 + threadIdx.x; e < 2*Nn; e += gridDim.x*256) {
        const int b = e / Nn, n = e % Nn;
        float4 v;
        v.x = kx[(b*3+0)*Nn + n]; v.y = kx[(b*3+1)*Nn + n];
        v.z = kx[(b*3+2)*Nn + n]; v.w = 0.f;
        kxt[e] = v;
    }
    for (int e = blockIdx.x*256 + threadIdx.x; e < 2*Mn; e += gridDim.x*256) {
        const int b = e / Mn, m = e % Mn;
        float4 v;
        v.x = q[(b*3+0)*Mn + m]; v.y = q[(b*3+1)*Mn + m];
        v.z = q[(b*3+2)*Mn + m]; v.w = 0.f;
        qt[e] = v;
    }
}

// ---------------- Kernel A: gather once -> x-cache (f16) + packed mask + moments ----------------
__global__ __launch_bounds__(256) void gatherx_kernel(
    const int* __restrict__ idx, const int* __restrict__ mask,
    float* __restrict__ ws)
{
    __shared__ float red[4][16];
    const int b = blockIdx.y;
    const float4* kxt = (const float4*)(ws + KXT_OFF) + (size_t)b*Nn;
    const float4* qt  = (const float4*)(ws + QT_OFF)  + (size_t)b*Mn;
    _Float16* xf = (_Float16*)(ws + XF_OFF);
    unsigned short* m16 = (unsigned short*)(ws + MSK_OFF) + (size_t)b*25024;
    float v[14];
#pragma unroll
    for (int j = 0; j < 14; ++j) v[j] = 0.f;

    for (int i = blockIdx.x*256 + threadIdx.x; i < MK; i += G1*256) {
        const int mm = i >> 4;
        const int id = idx[(size_t)b*MK + i];
        const float4 kv = kxt[id];
        const float4 qv = qt[mm];
        const float ox = kv.x - qv.x, oy = kv.y - qv.y, oz = kv.z - qv.z;
        const float d  = sqrtf(ox*ox + oy*oy + oz*oz);
        const float inv = 1.0f / fmaxf(d, 1e-12f);
        const float x0 = ox*inv, x1 = oy*inv, x2 = oz*inv, x3 = d;

        const hf2 lo = pkcvt(x0, x1);
        const hf2 hi = pkcvt(x2, x3);
        hf4 pk;
        pk[0] = lo[0]; pk[1] = lo[1]; pk[2] = hi[0]; pk[3] = hi[1];
        *(hf4*)&xf[((size_t)b*MK + i)*4] = pk;

        const unsigned long long mb = __ballot(mask[(size_t)b*MK + i] != 0);
        if ((threadIdx.x & 63) == 0)
            *(unsigned long long*)&m16[i >> 4] = mb;

        v[0] += x0; v[1] += x1; v[2] += x2; v[3] += x3;
        v[4] += x0*x0; v[5] += x0*x1; v[6] += x0*x2; v[7] += x0*x3;
        v[8] += x1*x1; v[9] += x1*x2; v[10] += x1*x3;
        v[11] += x2*x2; v[12] += x2*x3; v[13] += x3*x3;
    }
    const int lane = threadIdx.x & 63, wv = threadIdx.x >> 6;
#pragma unroll
    for (int j = 0; j < 14; ++j) v[j] = waveSum(v[j]);
    if (lane == 0) {
#pragma unroll
        for (int j = 0; j < 14; ++j) red[wv][j] = v[j];
    }
    __syncthreads();
    if (threadIdx.x < 14)
        ws[SP_OFF + ((size_t)b*G1 + blockIdx.x)*16 + threadIdx.x] =
            red[0][threadIdx.x] + red[1][threadIdx.x] + red[2][threadIdx.x] + red[3][threadIdx.x];
}

// ---------------- Kernel B: block0: moments -> gn1 fold + beff + ab2 prescale;
//                  blocks 1..16: Weff + f16 weight conversion (data-independent) ----------------
__global__ void prep1_kernel(
    const float* __restrict__ ws_r,
    const float* __restrict__ w1, const float* __restrict__ b1,
    const float* __restrict__ g1, const float* __restrict__ be1,
    const float* __restrict__ w2, const float* __restrict__ pe_b2,
    const float* __restrict__ aw1, const float* __restrict__ ab1,
    const float* __restrict__ aw2, const float* __restrict__ ab2,
    float* __restrict__ ws)
{
    const int t = threadIdx.x;
    _Float16* WF = (_Float16*)(ws + WF16_OFF);

    if (blockIdx.x > 0) {
        // one element per thread: 16 blocks x 256 threads = 4096 elements
        const int e = (blockIdx.x - 1)*256 + t;
        const int o = e >> 6, c = e & 63;
        WF[e]        = (_Float16)w2[e];
        WF[4096 + e] = (_Float16)(aw2[e] * LOG2E);
        float acc = 0.f;
        for (int d = 0; d < 64; ++d) acc = fmaf(aw1[o*64 + d], w2[d*64 + c], acc);
        WF[8192 + e] = (_Float16)acc;
        return;
    }

    __shared__ double S[2][14];
    __shared__ float Eh[2][64], Eq[2][64];

    if (t < 28) {
        const int b = t / 14, j = t % 14;
        const float* p = ws_r + SP_OFF + (size_t)b*G1*16 + j;
        double acc = 0.0;
        for (int g = 0; g < G1; g += 4)
            acc += (double)p[(g+0)*16] + (double)p[(g+1)*16]
                 + (double)p[(g+2)*16] + (double)p[(g+3)*16];
        S[b][j] = acc;
    }
    __syncthreads();

    if (t < 128) {
        const int b = t >> 6, o = t & 63;
        const double inv = 1.0 / (double)MK;
        double mu[4];
#pragma unroll
        for (int c = 0; c < 4; ++c) mu[c] = S[b][c] * inv;
        double m2[4][4];
        {
            const int map[4][4] = {{0,1,2,3},{1,4,5,6},{2,5,7,8},{3,6,8,9}};
#pragma unroll
            for (int c = 0; c < 4; ++c)
#pragma unroll
                for (int c2 = 0; c2 < 4; ++c2)
                    m2[c][c2] = S[b][4 + map[c][c2]] * inv;
        }
        double w[4];
#pragma unroll
        for (int c = 0; c < 4; ++c) w[c] = (double)w1[o*4 + c];
        double s = 0.0, qd = 0.0;
#pragma unroll
        for (int c = 0; c < 4; ++c) {
            s += w[c] * mu[c];
#pragma unroll
            for (int c2 = 0; c2 < 4; ++c2) qd += w[c]*w[c2]*m2[c][c2];
        }
        const double bb = (double)b1[o];
        Eh[b][o] = (float)(s + bb);
        Eq[b][o] = (float)(qd + 2.0*bb*s + bb*bb);
    }
    __syncthreads();
    if (t < 128) {
        const int b = t >> 6, o = t & 63, g = o & ~7;
        float mg = 0.f, qg = 0.f;
#pragma unroll
        for (int j = 0; j < 8; ++j) { mg += Eh[b][g + j]; qg += Eq[b][g + j]; }
        mg *= 0.125f; qg *= 0.125f;
        const float var = fmaxf(qg - mg*mg, 0.f);
        const float a = g1[o] / sqrtf(var + GN_EPS);
        const float c1v = be1[o] - mg*a;
        _Float16* W1F = (_Float16*)(ws + W1F_OFF);
        hf8 wrow;
#pragma unroll
        for (int c = 0; c < 4; ++c) wrow[c] = (_Float16)(a * w1[o*4 + c]);
#pragma unroll
        for (int c = 4; c < 8; ++c) wrow[c] = (_Float16)0.f;
        *(hf8*)&W1F[(b*64 + o)*8] = wrow;
        ws[B1P_OFF + b*64 + o] = fmaf(a, b1[o], c1v);
    }
    if (t < 64) {
        float acc = ab1[t];
        for (int d = 0; d < 64; ++d) acc = fmaf(aw1[t*64 + d], pe_b2[d], acc);
        ws[BEFF_OFF + t] = acc;
    } else if (t < 128) {
        ws[AB2L_OFF + (t - 64)] = ab2[t - 64] * LOG2E;
    }
}

// ---------------- Kernel C: Σy, Σy² (y = Weff@r1), all-MFMA, interleaved cols ----------------
__global__ __launch_bounds__(256, 4) void pass2_kernel(
    const float* __restrict__ cws, float* __restrict__ ws)
{
    __shared__ __align__(16) _Float16 Xs[4][32][72];
    const int b = blockIdx.y;
    const int tid = threadIdx.x, lane = tid & 63, wv = tid >> 6;
    const int colA = lane & 31;
    const int klo = (lane >> 5) * 8;
    const _Float16* xf  = (const _Float16*)(cws + XF_OFF);
    const _Float16* WFe = (const _Float16*)(cws + WF16_OFF) + 8192;  // Weff
    const _Float16* W1F = (const _Float16*)(cws + W1F_OFF);

    hf8 BW[2][4];
#pragma unroll
    for (int jc = 0; jc < 2; ++jc)
#pragma unroll
        for (int ks = 0; ks < 4; ++ks)
            BW[jc][ks] = *(const hf8*)&WFe[(2*colA + jc)*64 + 16*ks + klo];
    hf8 BX[2];
    if (klo == 0) {
        BX[0] = *(const hf8*)&W1F[(b*64 + 2*colA)*8];
        BX[1] = *(const hf8*)&W1F[(b*64 + 2*colA + 1)*8];
    } else { BX[0] = zero8(); BX[1] = zero8(); }
    const float bias0 = cws[B1P_OFF + b*64 + 2*colA];
    const float bias1 = cws[B1P_OFF + b*64 + 2*colA + 1];

    float sh[2] = {0.f, 0.f}, sq[2] = {0.f, 0.f};

    for (int base = blockIdx.x * 128; base < MK; base += G2 * 128) {
        const int pt0 = base + 32*wv;
        hf8 ax = zero8();
        if (klo == 0) {
            hf4 xv = *(const hf4*)&xf[((size_t)b*MK + pt0 + colA)*4];
#pragma unroll
            for (int j = 0; j < 4; ++j) ax[j] = xv[j];
        }
        f32x16 r0 = splat16(bias0), r1t = splat16(bias1);
        r0  = mfma16(ax, BX[0], r0);
        r1t = mfma16(ax, BX[1], r1t);
#pragma unroll
        for (int r = 0; r < 16; ++r) {
            const int row = ROWFN(r, lane);
            *(hf2*)&Xs[wv][row][2*colA] = pkrelu(pkcvt(r0[r], r1t[r]));
        }
        hf8 A[4];
#pragma unroll
        for (int ks = 0; ks < 4; ++ks)
            A[ks] = *(const hf8*)&Xs[wv][colA][16*ks + klo];
#pragma unroll
        for (int jc = 0; jc < 2; ++jc) {
            f32x16 C = splat16(0.f);
#pragma unroll
            for (int ks = 0; ks < 4; ++ks) C = mfma16(A[ks], BW[jc][ks], C);
#pragma unroll
            for (int r = 0; r < 16; ++r) {
                const float vy = C[r];
                sh[jc] += vy;
                sq[jc] = fmaf(vy, vy, sq[jc]);
            }
        }
    }

#pragma unroll
    for (int jc = 0; jc < 2; ++jc) {
        sh[jc] += __shfl_xor(sh[jc], 32, 64);
        sq[jc] += __shfl_xor(sq[jc], 32, 64);
    }
    __syncthreads();
    float* red = (float*)Xs;   // [4][128]
    if (lane < 32) {
#pragma unroll
        for (int jc = 0; jc < 2; ++jc) {
            red[wv*128 +      2*colA + jc] = sh[jc];
            red[wv*128 + 64 + 2*colA + jc] = sq[jc];
        }
    }
    __syncthreads();
    if (tid < 128) {
        const float v = red[tid] + red[128 + tid] + red[256 + tid] + red[384 + tid];
        ws[YP_OFF + ((size_t)b*G2 + blockIdx.x)*128 + tid] = v;
    }
}

// ---------------- Kernel D1: parallel reduce of pass2 partials (one block per output) ----------------
__global__ __launch_bounds__(64) void prep2a_kernel(
    const float* __restrict__ ws_r, float* __restrict__ ws)
{
    const int o2 = blockIdx.x;            // [0,256): b = o2>>7, i = o2&127
    const int b = o2 >> 7, i = o2 & 127;
    const float* p = ws_r + YP_OFF + (size_t)b*G2*128 + i;
    double acc = 0.0;
    for (int g = threadIdx.x; g < G2; g += 64) acc += (double)p[(size_t)g*128];
#pragma unroll
    for (int s = 32; s; s >>= 1) acc += __shfl_down(acc, s, 64);
    if (threadIdx.x == 0) ((double*)(ws + YS_OFF))[o2] = acc;
}

// ---------------- Kernel D2: gn2 coeffs + fold into aw1/ab1 ----------------
__global__ void prep2b_kernel(const float* __restrict__ ws_r,
                              const float* __restrict__ g2, const float* __restrict__ be2,
                              const float* __restrict__ aw1, const float* __restrict__ ab1,
                              float* __restrict__ ws)
{
    __shared__ float EH[2][64], EQ[2][64];
    __shared__ float A2s[2][64];
    const int t = threadIdx.x;   // 256
    const double* YS = (const double*)(ws_r + YS_OFF);
    if (t < 128) {
        const int b = t >> 6, o = t & 63;
        const double invMK = 1.0 / (double)MK;
        const double my = YS[b*128 + o] * invMK;
        const double qy = YS[b*128 + 64 + o] * invMK;
        const double beff = (double)ws_r[BEFF_OFF + o];
        EH[b][o] = (float)(my + beff);
        EQ[b][o] = (float)(qy + 2.0*beff*my + beff*beff);
    }
    __syncthreads();
    if (t < 128) {
        const int b = t >> 6, o = t & 63, g = o & ~7;
        float mg = 0.f, qg = 0.f;
#pragma unroll
        for (int j = 0; j < 8; ++j) { mg += EH[b][g + j]; qg += EQ[b][g + j]; }
        mg *= 0.125f; qg *= 0.125f;
        const float var = fmaxf(qg - mg*mg, 0.f);
        const float a = g2[o] / sqrtf(var + GN_EPS);
        A2s[b][o] = a;
        ws[AB1P_OFF + b*64 + o] = fmaf(a, ab1[o], be2[o] - mg*a);
    }
    __syncthreads();
    _Float16* AW1P = (_Float16*)(ws + AW1P_OFF);
    for (int e = t; e < 8192; e += 256) {
        const int b = e >> 12, oc = e & 4095, o = oc >> 6;
        AW1P[e] = (_Float16)(A2s[b][o] * aw1[oc]);
    }
}

// ---------------- Kernel E: two-tile all-MFMA forward (64 pts/wave, B-fragments reused) ----------------
__global__ __launch_bounds__(256, 3) void pass3_kernel(
    const float* __restrict__ b2,
    const float* __restrict__ cws, float* __restrict__ out)
{
    __shared__ __align__(16) _Float16 Xs[8][32][72];   // [2*wv+t][row][col] 36.9 KB
    float* O = (float*)Xs;                             // aliased after barrier: [64][17]

    const int b = blockIdx.y;
    const int base = blockIdx.x * 256;                 // grid.x = 1563; last block partial
    const int tid = threadIdx.x;
    const int lane = tid & 63, wv = tid >> 6;
    const int colA = lane & 31;
    const int klo = (lane >> 5) * 8;

    const _Float16* xf   = (const _Float16*)(cws + XF_OFF);
    const _Float16* WF   = (const _Float16*)(cws + WF16_OFF);
    const _Float16* AW1P = (const _Float16*)(cws + AW1P_OFF) + (size_t)b*4096;
    const _Float16* W1F  = (const _Float16*)(cws + W1F_OFF);
    const unsigned short* m16 = (const unsigned short*)(cws + MSK_OFF) + (size_t)b*25024;

    int pt0[2];
    pt0[0] = base + 64*wv;
    pt0[1] = base + 64*wv + 32;
    unsigned mb[2];
#pragma unroll
    for (int t = 0; t < 2; ++t)
        mb[t] = (pt0[t] < MK) ? *(const unsigned*)(m16 + (pt0[t] >> 4)) : 0u;
    const unsigned mbs0 = __builtin_amdgcn_readfirstlane(mb[0]);
    const unsigned mbs1 = __builtin_amdgcn_readfirstlane(mb[1]);

    // ---- r1 via MFMA from cached x (both tiles; BX shared) ----
    {
        hf8 BX0, BX1;
        if (klo == 0) {
            BX0 = *(const hf8*)&W1F[(b*64 + 2*colA)*8];
            BX1 = *(const hf8*)&W1F[(b*64 + 2*colA + 1)*8];
        } else { BX0 = zero8(); BX1 = zero8(); }
        const float bias0 = cws[B1P_OFF + b*64 + 2*colA];
        const float bias1 = cws[B1P_OFF + b*64 + 2*colA + 1];
#pragma unroll
        for (int t = 0; t < 2; ++t) {
            hf8 ax = zero8();
            if (klo == 0 && pt0[t] < MK) {
                hf4 xv = *(const hf4*)&xf[((size_t)b*MK + pt0[t] + colA)*4];
#pragma unroll
                for (int j = 0; j < 4; ++j) ax[j] = xv[j];
            }
            f32x16 r0 = splat16(bias0), r1t = splat16(bias1);
            r0  = mfma16(ax, BX0, r0);
            r1t = mfma16(ax, BX1, r1t);
#pragma unroll
            for (int r = 0; r < 16; ++r) {
                const int row = ROWFN(r, lane);
                *(hf2*)&Xs[2*wv + t][row][2*colA] = pkrelu(pkcvt(r0[r], r1t[r]));
            }
            // mask bias into pad cols [64..71]: full 8-half write (no uninit LDS)
            if (lane < 32) {
                hf8 pad = zero8();
                pad[0] = ((mb[t] >> lane) & 1u) ? (_Float16)0.f : (_Float16)(-60000.f);
                *(hf8*)&Xs[2*wv + t][lane][64] = pad;
            }
        }
    }

    // ---- GEMM1: pe = r1 @ w2^T + b2 (B reused across tiles) ----
    hf2 pe_pk[2][16];   // packed pe kept for softmax (32 VGPRs)
    {
        f32x16 p00 = splat16(b2[2*colA]);
        f32x16 p01 = splat16(b2[2*colA + 1]);
        f32x16 p10 = p00, p11 = p01;
#pragma unroll
        for (int ks = 0; ks < 4; ++ks) {
            const int off = 16*ks + klo;
            hf8 a0  = *(const hf8*)&Xs[2*wv    ][colA][off];
            hf8 a1  = *(const hf8*)&Xs[2*wv + 1][colA][off];
            hf8 b0f = *(const hf8*)&WF[(2*colA)*64 + off];
            hf8 b1f = *(const hf8*)&WF[(2*colA + 1)*64 + off];
            p00 = mfma16(a0, b0f, p00);
            p01 = mfma16(a0, b1f, p01);
            p10 = mfma16(a1, b0f, p10);
            p11 = mfma16(a1, b1f, p11);
        }
#pragma unroll
        for (int r = 0; r < 16; ++r) {
            const int row = ROWFN(r, lane);
            pe_pk[0][r] = pkcvt(p00[r], p01[r]);
            pe_pk[1][r] = pkcvt(p10[r], p11[r]);
            *(hf2*)&Xs[2*wv    ][row][2*colA] = pe_pk[0][r];
            *(hf2*)&Xs[2*wv + 1][row][2*colA] = pe_pk[1][r];
        }
    }

    // ---- GEMM2: r2 = relu(pe @ (a2*aw1)^T + ab1') ----
    {
        f32x16 h00 = splat16(cws[AB1P_OFF + b*64 + 2*colA]);
        f32x16 h01 = splat16(cws[AB1P_OFF + b*64 + 2*colA + 1]);
        f32x16 h10 = h00, h11 = h01;
#pragma unroll
        for (int ks = 0; ks < 4; ++ks) {
            const int off = 16*ks + klo;
            hf8 a0  = *(const hf8*)&Xs[2*wv    ][colA][off];
            hf8 a1  = *(const hf8*)&Xs[2*wv + 1][colA][off];
            hf8 b0f = *(const hf8*)&AW1P[(2*colA)*64 + off];
            hf8 b1f = *(const hf8*)&AW1P[(2*colA + 1)*64 + off];
            h00 = mfma16(a0, b0f, h00);
            h01 = mfma16(a0, b1f, h01);
            h10 = mfma16(a1, b0f, h10);
            h11 = mfma16(a1, b1f, h11);
        }
#pragma unroll
        for (int r = 0; r < 16; ++r) {
            const int row = ROWFN(r, lane);
            *(hf2*)&Xs[2*wv    ][row][2*colA] = pkrelu(pkcvt(h00[r], h01[r]));
            *(hf2*)&Xs[2*wv + 1][row][2*colA] = pkrelu(pkcvt(h10[r], h11[r]));
        }
    }

    // ---- GEMM3: logits(log2) = r2 @ (aw2*log2e)^T + ab2*log2e + mask rank-1 ----
    f32x16 l00 = splat16(cws[AB2L_OFF + 2*colA]);
    f32x16 l01 = splat16(cws[AB2L_OFF + 2*colA + 1]);
    f32x16 l10 = l00, l11 = l01;
#pragma unroll
    for (int ks = 0; ks < 4; ++ks) {
        const int off = 16*ks + klo;
        hf8 a0  = *(const hf8*)&Xs[2*wv    ][colA][off];
        hf8 a1  = *(const hf8*)&Xs[2*wv + 1][colA][off];
        hf8 b0f = *(const hf8*)&WF[4096 + (2*colA)*64 + off];
        hf8 b1f = *(const hf8*)&WF[4096 + (2*colA + 1)*64 + off];
        l00 = mfma16(a0, b0f, l00);
        l01 = mfma16(a0, b1f, l01);
        l10 = mfma16(a1, b0f, l10);
        l11 = mfma16(a1, b1f, l11);
    }
    {
        hf8 b5 = zero8();
        if (klo == 0) b5[0] = (_Float16)1.f;
        hf8 a50 = zero8(), a51 = zero8();
        if (klo == 0) {
            a50 = *(const hf8*)&Xs[2*wv    ][colA][64];
            a51 = *(const hf8*)&Xs[2*wv + 1][colA][64];
        }
        l00 = mfma16(a50, b5, l00);
        l01 = mfma16(a50, b5, l01);
        l10 = mfma16(a51, b5, l10);
        l11 = mfma16(a51, b5, l11);
    }

    __syncthreads();   // all Xs reads done; O may alias Xs

    // ---- softmax over K=16 (exp2 domain) + weighted pe sum ----
    {
        auto softmax_tile = [&](const f32x16& lg, const hf2* pp, unsigned mbst,
                                int t, int j) {
#pragma unroll
            for (int mh = 0; mh < 2; ++mh) {
                float mx = lg[8*mh];
#pragma unroll
                for (int rr = 1; rr < 8; ++rr) mx = fmaxf(mx, lg[8*mh + rr]);
                mx = fmaxf(mx, __shfl_xor(mx, 32, 64));
                float se, sw = 0.f;
                if (((mbst >> (16*mh)) & 0xFFFFu) != 0u) {
                    se = 0.f;
#pragma unroll
                    for (int rr = 0; rr < 8; ++rr) {
                        const float e = exp2f(lg[8*mh + rr] - mx);
                        se += e;
                        sw = fmaf(e, (float)pp[8*mh + rr][j], sw);
                    }
                } else {
                    se = 8.f;
#pragma unroll
                    for (int rr = 0; rr < 8; ++rr) sw += (float)pp[8*mh + rr][j];
                }
                se += __shfl_xor(se, 32, 64);
                sw += __shfl_xor(sw, 32, 64);
                if (lane < 32)
                    O[(2*lane + j)*17 + (4*wv + 2*t + mh)] = sw * __builtin_amdgcn_rcpf(se);
            }
        };
        softmax_tile(l00, pe_pk[0], mbs0, 0, 0);
        softmax_tile(l01, pe_pk[0], mbs0, 0, 1);
        softmax_tile(l10, pe_pk[1], mbs1, 1, 0);
        softmax_tile(l11, pe_pk[1], mbs1, 1, 1);
    }
    __syncthreads();

    {   // 64 ch x 16 m per block, one float4 per thread
        const int o = tid >> 2, mq = (tid & 3) * 4;
        const int m0 = blockIdx.x * 16;
        if (m0 + mq < Mn) {
            float4 v;
            v.x = O[o*17 + mq];     v.y = O[o*17 + mq + 1];
            v.z = O[o*17 + mq + 2]; v.w = O[o*17 + mq + 3];
            *(float4*)&out[((size_t)b*64 + o)*Mn + m0 + mq] = v;
        }
    }
}

extern "C" void kernel_launch(void* const* d_in, const int* in_sizes, int n_in,
                              void* d_out, int out_size, void* d_ws, size_t ws_size,
                              hipStream_t stream) {
    (void)in_sizes; (void)n_in; (void)out_size; (void)ws_size;
    const float* q    = (const float*)d_in[0];
    const float* kx   = (const float*)d_in[1];
    const int*   idx  = (const int*)  d_in[2];
    const int*   mask = (const int*)  d_in[3];
    const float* w1   = (const float*)d_in[4];
    const float* b1   = (const float*)d_in[5];
    const float* g1   = (const float*)d_in[6];
    const float* be1  = (const float*)d_in[7];
    const float* w2   = (const float*)d_in[8];
    const float* b2   = (const float*)d_in[9];
    const float* aw1  = (const float*)d_in[10];
    const float* ab1  = (const float*)d_in[11];
    const float* g2   = (const float*)d_in[12];
    const float* be2  = (const float*)d_in[13];
    const float* aw2  = (const float*)d_in[14];
    const float* ab2  = (const float*)d_in[15];
    float* out = (float*)d_out;
    float* ws  = (float*)d_ws;

    prep0_kernel<<<256, 256, 0, stream>>>(q, kx, ws);
    gatherx_kernel<<<dim3(G1, Bn), 256, 0, stream>>>(idx, mask, ws);
    prep1_kernel<<<17, 256, 0, stream>>>(ws, w1, b1, g1, be1, w2, b2, aw1, ab1, aw2, ab2, ws);
    pass2_kernel<<<dim3(G2, Bn), 256, 0, stream>>>(ws, ws);
    prep2a_kernel<<<256, 64, 0, stream>>>(ws, ws);
    prep2b_kernel<<<1, 256, 0, stream>>>(ws, g2, be2, aw1, ab1, ws);
    pass3_kernel<<<dim3((MK + 255)/256, Bn), 256, 0, stream>>>(b2, ws, out);
}